// Round 5
// baseline (1573.704 us; speedup 1.0000x reference)
//
#include <hip/hip_runtime.h>
#include <hip/hip_bf16.h>

#define NNODES 100000
#define NEDGES 3200000
#define NG     64
#define NBUCK  196          // ceil(NNODES/512) buckets of 512 dst nodes
#define PB     256          // phase-A partition blocks

// ---------- dtype-flexible loads (flags are wave-uniform) ----------
__device__ __forceinline__ int ld_idx(const void* p, long long i, int is64) {
    if (is64) return (int)((const long long*)p)[i];
    return ((const int*)p)[i];
}
__device__ __forceinline__ float ld_f(const void* p, long long i, int isf32) {
    if (isf32) return ((const float*)p)[i];
    return __bfloat162float(((const __hip_bfloat16*)p)[i]);
}
__device__ __forceinline__ float bfbits(unsigned b) {
    return __uint_as_float(b << 16);
}

// ---------- runtime dtype detection (proven) ----------
__global__ void detect_kernel(const void* x, const void* ei, const void* bat, int* flags) {
    if (threadIdx.x != 0 || blockIdx.x != 0) return;
    const unsigned short* u = (const unsigned short*)x;
    int isf32 = 0;
    for (int i = 0; i < 256; ++i) {
        int e = (u[i] >> 7) & 0xFF;
        if (e >= 0x90) { isf32 = 1; break; }
    }
    const unsigned* w = (const unsigned*)ei;
    int ei64 = 1;
    for (int j = 1; j < 256; j += 2) if (w[j] != 0u) { ei64 = 0; break; }
    const unsigned* bw = (const unsigned*)bat;
    int b64 = 1;
    for (int j = 50001; j < 50001 + 256; j += 2) if (bw[j] != 0u) { b64 = 0; break; }
    flags[0] = isf32; flags[1] = ei64; flags[2] = b64;
}

// ---------- phase A1: per-(bucket,block) edge counts (LDS only) ----------
__global__ void binA_count(const void* ei, const int* __restrict__ flags,
                           int* __restrict__ bcnt, int E) {
    __shared__ int cnt[NBUCK];
    int is64 = flags[1];
    for (int i = threadIdx.x; i < NBUCK; i += 256) cnt[i] = 0;
    __syncthreads();
    const int chunk = (E + PB - 1) / PB;
    int beg = blockIdx.x * chunk, end = min(E, beg + chunk);
    for (int i = beg + threadIdx.x; i < end; i += 256) {
        int s = ld_idx(ei, i, is64);
        int d = ld_idx(ei, (long long)E + i, is64);
        if ((unsigned)s < (unsigned)NNODES && (unsigned)d < (unsigned)NNODES)
            atomicAdd(&cnt[d >> 9], 1);
    }
    __syncthreads();
    for (int i = threadIdx.x; i < NBUCK; i += 256)
        bcnt[i * PB + blockIdx.x] = cnt[i];     // bucket-major for scan
}

// ---------- phase A2: exclusive scan over PB*NBUCK counts (in place) ----------
__global__ void binA_scan(int* __restrict__ bcnt) {
    __shared__ int ls[1024];
    const int M = PB * NBUCK;
    const int CH = (M + 1023) / 1024;
    int t = threadIdx.x;
    int beg = t * CH, end = min(M, beg + CH);
    int sum = 0;
    for (int i = beg; i < end; ++i) sum += bcnt[i];
    ls[t] = sum;
    __syncthreads();
    for (int off = 1; off < 1024; off <<= 1) {
        int v = (t >= off) ? ls[t - off] : 0;
        __syncthreads();
        ls[t] += v;
        __syncthreads();
    }
    int run = ls[t] - sum;
    for (int i = beg; i < end; ++i) {
        int c = bcnt[i];
        bcnt[i] = run;
        run += c;
    }
    if (t == 1023) bcnt[M] = ls[1023];          // total staged edges
}

// ---------- phase A3: partition edges into bucket-ordered staging (s,d) ----------
__global__ void binA_write(const void* ei, const int* __restrict__ flags,
                           const int* __restrict__ bcnt, uint2* __restrict__ staging, int E) {
    __shared__ int cur[NBUCK];
    int is64 = flags[1];
    for (int i = threadIdx.x; i < NBUCK; i += 256) cur[i] = bcnt[i * PB + blockIdx.x];
    __syncthreads();
    const int chunk = (E + PB - 1) / PB;
    int beg = blockIdx.x * chunk, end = min(E, beg + chunk);
    for (int i = beg + threadIdx.x; i < end; i += 256) {
        int s = ld_idx(ei, i, is64);
        int d = ld_idx(ei, (long long)E + i, is64);
        if ((unsigned)s < (unsigned)NNODES && (unsigned)d < (unsigned)NNODES) {
            int pos = atomicAdd(&cur[d >> 9], 1);
            staging[pos] = make_uint2((unsigned)s, (unsigned)d);
        }
    }
}

// ---------- phase B1: per-bucket node degrees (LDS counters, no global atomics) ----------
__global__ void binB_deg(const uint2* __restrict__ staging, const int* __restrict__ bcnt,
                         int* __restrict__ deg) {
    __shared__ int dcnt[512];
    int b = blockIdx.x;
    int lo = b << 9;
    for (int i = threadIdx.x; i < 512; i += 256) dcnt[i] = 0;
    __syncthreads();
    int beg = bcnt[b * PB], end = bcnt[(b + 1) * PB];
    for (int i = beg + threadIdx.x; i < end; i += 256)
        atomicAdd(&dcnt[staging[i].y - lo], 1);
    __syncthreads();
    for (int i = threadIdx.x; i < 512; i += 256)
        if (lo + i < NNODES) deg[lo + i] = dcnt[i];
}

__global__ void dinv_kernel(const int* __restrict__ deg, float* __restrict__ dinv, int N) {
    int i = blockIdx.x * blockDim.x + threadIdx.x;
    if (i < N) dinv[i] = rsqrtf((float)deg[i] + 1.0f);   // +1 = self-loop
}

// ---------- exclusive scan deg -> row_start ----------
__global__ void scan_kernel(int* __restrict__ deg, int* __restrict__ row_start, int N) {
    __shared__ int ls[1024];
    const int CH = (N + 1023) / 1024;
    int t = threadIdx.x;
    int beg = t * CH, end = min(N, beg + CH);
    int sum = 0;
    for (int i = beg; i < end; ++i) sum += deg[i];
    ls[t] = sum;
    __syncthreads();
    for (int off = 1; off < 1024; off <<= 1) {
        int v = (t >= off) ? ls[t - off] : 0;
        __syncthreads();
        ls[t] += v;
        __syncthreads();
    }
    int run = ls[t] - sum;
    for (int i = beg; i < end; ++i) {
        row_start[i] = run;
        run += deg[i];
    }
    if (t == 1023) row_start[N] = ls[1023];
}

// ---------- phase B2: per-bucket CSR fill (LDS cursors; writes stay in 65KB region) ----------
__global__ void binB_fill(const uint2* __restrict__ staging, const int* __restrict__ bcnt,
                          const int* __restrict__ rs, int* __restrict__ csr) {
    __shared__ int cur[512];
    int b = blockIdx.x;
    int lo = b << 9;
    for (int i = threadIdx.x; i < 512; i += 256)
        cur[i] = (lo + i < NNODES) ? rs[lo + i] : 0;
    __syncthreads();
    int beg = bcnt[b * PB], end = bcnt[(b + 1) * PB];
    for (int i = beg + threadIdx.x; i < end; i += 256) {
        uint2 u = staging[i];
        int pos = atomicAdd(&cur[u.y - lo], 1);
        csr[pos] = (int)u.x;
    }
}

// ---------- GEMM: W in LDS, 4 rows/wave; optional dinv[row] output scaling ----------
// SRC==0: X has detected dtype; SRC==1: X is fp32 workspace
template <int K, int SRC>
__global__ void gemm_lds(const void* __restrict__ X, const void* __restrict__ W,
                         const int* __restrict__ flags, const float* __restrict__ dscale,
                         float* __restrict__ Out, int N) {
    __shared__ float lsW[K * 64];
    int isf32 = flags[0];
    for (int i = threadIdx.x; i < K * 64; i += 256) lsW[i] = ld_f(W, i, isf32);
    __syncthreads();

    int c = threadIdx.x & 63;
    int wave = blockIdx.x * 4 + (threadIdx.x >> 6);
    int nwaves = gridDim.x * 4;
    int ngroups = (N + 3) >> 2;

    for (int g = wave; g < ngroups; g += nwaves) {
        int base = g * 4;
        float acc0 = 0.f, acc1 = 0.f, acc2 = 0.f, acc3 = 0.f;
        if (base + 3 < N) {
            if (SRC == 1 || isf32) {
                const float4* x0 = (const float4*)((const float*)X + (long long)(base + 0) * K);
                const float4* x1 = (const float4*)((const float*)X + (long long)(base + 1) * K);
                const float4* x2 = (const float4*)((const float*)X + (long long)(base + 2) * K);
                const float4* x3 = (const float4*)((const float*)X + (long long)(base + 3) * K);
#pragma unroll
                for (int k4 = 0; k4 < K / 4; ++k4) {
                    float4 a0 = x0[k4], a1 = x1[k4], a2 = x2[k4], a3 = x3[k4];
                    float w0 = lsW[(4 * k4 + 0) * 64 + c];
                    float w1 = lsW[(4 * k4 + 1) * 64 + c];
                    float w2 = lsW[(4 * k4 + 2) * 64 + c];
                    float w3 = lsW[(4 * k4 + 3) * 64 + c];
                    acc0 += a0.x * w0 + a0.y * w1 + a0.z * w2 + a0.w * w3;
                    acc1 += a1.x * w0 + a1.y * w1 + a1.z * w2 + a1.w * w3;
                    acc2 += a2.x * w0 + a2.y * w1 + a2.z * w2 + a2.w * w3;
                    acc3 += a3.x * w0 + a3.y * w1 + a3.z * w2 + a3.w * w3;
                }
            } else {
                const uint2* x0 = (const uint2*)((const unsigned short*)X + (long long)(base + 0) * K);
                const uint2* x1 = (const uint2*)((const unsigned short*)X + (long long)(base + 1) * K);
                const uint2* x2 = (const uint2*)((const unsigned short*)X + (long long)(base + 2) * K);
                const uint2* x3 = (const uint2*)((const unsigned short*)X + (long long)(base + 3) * K);
#pragma unroll
                for (int k4 = 0; k4 < K / 4; ++k4) {
                    uint2 u0 = x0[k4], u1 = x1[k4], u2 = x2[k4], u3 = x3[k4];
                    float w0 = lsW[(4 * k4 + 0) * 64 + c];
                    float w1 = lsW[(4 * k4 + 1) * 64 + c];
                    float w2 = lsW[(4 * k4 + 2) * 64 + c];
                    float w3 = lsW[(4 * k4 + 3) * 64 + c];
                    acc0 += bfbits(u0.x & 0xffffu) * w0 + bfbits(u0.x >> 16) * w1
                          + bfbits(u0.y & 0xffffu) * w2 + bfbits(u0.y >> 16) * w3;
                    acc1 += bfbits(u1.x & 0xffffu) * w0 + bfbits(u1.x >> 16) * w1
                          + bfbits(u1.y & 0xffffu) * w2 + bfbits(u1.y >> 16) * w3;
                    acc2 += bfbits(u2.x & 0xffffu) * w0 + bfbits(u2.x >> 16) * w1
                          + bfbits(u2.y & 0xffffu) * w2 + bfbits(u2.y >> 16) * w3;
                    acc3 += bfbits(u3.x & 0xffffu) * w0 + bfbits(u3.x >> 16) * w1
                          + bfbits(u3.y & 0xffffu) * w2 + bfbits(u3.y >> 16) * w3;
                }
            }
            float d0 = 1.f, d1 = 1.f, d2 = 1.f, d3 = 1.f;
            if (dscale) { d0 = dscale[base]; d1 = dscale[base + 1]; d2 = dscale[base + 2]; d3 = dscale[base + 3]; }
            Out[(long long)(base + 0) * 64 + c] = acc0 * d0;
            Out[(long long)(base + 1) * 64 + c] = acc1 * d1;
            Out[(long long)(base + 2) * 64 + c] = acc2 * d2;
            Out[(long long)(base + 3) * 64 + c] = acc3 * d3;
        } else {
            for (int r = base; r < N; ++r) {
                float s = 0.f;
                for (int k = 0; k < K; ++k) {
                    float xv = (SRC == 1) ? ((const float*)X)[(long long)r * K + k]
                                          : ld_f(X, (long long)r * K + k, isf32);
                    s += xv * lsW[k * 64 + c];
                }
                if (dscale) s *= dscale[r];
                Out[(long long)r * 64 + c] = s;
            }
        }
    }
}

// ---------- CSR gather over pre-scaled Hs (= dinv[n]*H[n]); no dinv in inner loop ----------
__global__ void gather_kernel(const float* __restrict__ Hs,
                              const int* __restrict__ row_start,
                              const int* __restrict__ csr_src,
                              const float* __restrict__ dinv,
                              const void* bias, const int* __restrict__ flags,
                              float* __restrict__ Hout, int N) {
    int isf32 = flags[0];
    int c = threadIdx.x & 63;
    int n = blockIdx.x * 4 + (threadIdx.x >> 6);
    if (n >= N) return;
    int beg = row_start[n], end = row_start[n + 1];
    float a0 = Hs[(long long)n * 64 + c];     // self-loop term (already ×dinv[n])
    float a1 = 0.f;
    int i = beg;
    for (; i + 3 < end; i += 4) {
        int s0 = csr_src[i], s1 = csr_src[i + 1], s2 = csr_src[i + 2], s3 = csr_src[i + 3];
        float h0 = Hs[(long long)s0 * 64 + c];
        float h1 = Hs[(long long)s1 * 64 + c];
        float h2 = Hs[(long long)s2 * 64 + c];
        float h3 = Hs[(long long)s3 * 64 + c];
        a0 += h0 + h2;
        a1 += h1 + h3;
    }
    for (; i < end; ++i)
        a0 += Hs[(long long)csr_src[i] * 64 + c];
    float v = (a0 + a1) * dinv[n] + ld_f(bias, c, isf32);
    Hout[(long long)n * 64 + c] = v > 0.f ? v : 0.f;
}

// ---------- pooling over final H ----------
__global__ void pool2_kernel(const float* __restrict__ H, const void* batch,
                             const int* __restrict__ flags,
                             float* __restrict__ pooled, float* __restrict__ cnt, int N) {
    __shared__ float part[NG * 64];
    __shared__ float scnt[NG];
    int b64 = flags[2];
    int tid = threadIdx.x;
    for (int i = tid; i < NG * 64; i += blockDim.x) part[i] = 0.f;
    if (tid < NG) scnt[tid] = 0.f;
    __syncthreads();
    int c = tid & 63;
    int sub = tid >> 6;
    for (int n = blockIdx.x * 4 + sub; n < N; n += gridDim.x * 4) {
        int g = ld_idx(batch, n, b64);
        if ((unsigned)g >= (unsigned)NG) continue;
        atomicAdd(&part[g * 64 + c], H[(long long)n * 64 + c]);
        if (c == 0) atomicAdd(&scnt[g], 1.0f);
    }
    __syncthreads();
    for (int i = tid; i < NG * 64; i += blockDim.x) {
        float v = part[i];
        if (v != 0.f) atomicAdd(&pooled[i], v);
    }
    if (tid < NG && scnt[tid] != 0.f) atomicAdd(&cnt[tid], scnt[tid]);
}

// ---------- final ----------
__global__ void final_kernel(const float* __restrict__ pooled, const float* __restrict__ cnt,
                             const void* lw, const void* lb,
                             const int* __restrict__ flags, void* out) {
    int isf32 = flags[0];
    int g = threadIdx.x;
    if (g >= NG) return;
    float inv = 1.0f / fmaxf(cnt[g], 1.0f);
    float logits[10];
    for (int c = 0; c < 10; ++c) logits[c] = ld_f(lb, c, isf32);
    for (int k = 0; k < 64; ++k) {
        float m = pooled[g * 64 + k] * inv;
        for (int c = 0; c < 10; ++c)
            logits[c] += m * ld_f(lw, k * 10 + c, isf32);
    }
    float mx = logits[0];
    for (int c = 1; c < 10; ++c) mx = fmaxf(mx, logits[c]);
    float se = 0.f;
    for (int c = 0; c < 10; ++c) se += __expf(logits[c] - mx);
    float lse = mx + __logf(se);
    if (isf32) {
        float* o = (float*)out;
        for (int c = 0; c < 10; ++c) o[g * 10 + c] = logits[c] - lse;
    } else {
        __hip_bfloat16* o = (__hip_bfloat16*)out;
        for (int c = 0; c < 10; ++c) o[g * 10 + c] = __float2bfloat16(logits[c] - lse);
    }
}

// ---------- fallback pipeline kernels (round-2 proven, atomic scatter) ----------
__global__ void count_kernel(const void* ei, const int* __restrict__ flags,
                             int* __restrict__ deg, int E) {
    int is64 = flags[1];
    int i = blockIdx.x * blockDim.x + threadIdx.x;
    int stride = gridDim.x * blockDim.x;
    for (; i < E; i += stride) {
        int d = ld_idx(ei, (long long)E + i, is64);
        if ((unsigned)d < (unsigned)NNODES) atomicAdd(&deg[d], 1);
    }
}

__global__ void scatter_kernel(const float* __restrict__ H, const void* ei,
                               const int* __restrict__ flags,
                               const float* __restrict__ dinv,
                               float* __restrict__ agg, int E) {
    int is64 = flags[1];
    int lane = threadIdx.x & 63;
    int e = blockIdx.x * 4 + (threadIdx.x >> 6);
    if (e >= E) return;
    int s = ld_idx(ei, e, is64);
    int d = ld_idx(ei, (long long)E + e, is64);
    if ((unsigned)s >= (unsigned)NNODES || (unsigned)d >= (unsigned)NNODES) return;
    float nrm = dinv[s] * dinv[d];
    float v = H[(long long)s * 64 + lane] * nrm;
    atomicAdd(&agg[(long long)d * 64 + lane], v);
}

__global__ void relu_bias_kernel(float* __restrict__ H, const float* __restrict__ agg,
                                 const float* __restrict__ dinv, const void* b,
                                 const int* __restrict__ flags, int N) {
    int isf32 = flags[0];
    long long idx = (long long)blockIdx.x * blockDim.x + threadIdx.x;
    if (idx >= (long long)N * 64) return;
    int n = (int)(idx >> 6);
    int c = (int)(idx & 63);
    float dv = dinv[n];
    float v = agg[idx] + H[idx] * dv * dv + ld_f(b, c, isf32);
    H[idx] = v > 0.f ? v : 0.f;
}

__global__ void pool_fb_kernel(const float* __restrict__ agg, const float* __restrict__ Hg,
                               const float* __restrict__ dinv, const void* b,
                               const void* batch, const int* __restrict__ flags,
                               float* __restrict__ pooled, float* __restrict__ cnt, int N) {
    __shared__ float part[NG * 64];
    __shared__ float scnt[NG];
    int isf32 = flags[0];
    int b64   = flags[2];
    int tid = threadIdx.x;
    for (int i = tid; i < NG * 64; i += blockDim.x) part[i] = 0.f;
    if (tid < NG) scnt[tid] = 0.f;
    __syncthreads();
    int c = tid & 63;
    int sub = tid >> 6;
    float bc = ld_f(b, c, isf32);
    for (int n = blockIdx.x * 4 + sub; n < N; n += gridDim.x * 4) {
        int g = ld_idx(batch, n, b64);
        if ((unsigned)g >= (unsigned)NG) continue;
        float dv = dinv[n];
        float v = agg[(long long)n * 64 + c] + Hg[(long long)n * 64 + c] * dv * dv + bc;
        v = v > 0.f ? v : 0.f;
        atomicAdd(&part[g * 64 + c], v);
        if (c == 0) atomicAdd(&scnt[g], 1.0f);
    }
    __syncthreads();
    for (int i = tid; i < NG * 64; i += blockDim.x) {
        float v = part[i];
        if (v != 0.f) atomicAdd(&pooled[i], v);
    }
    if (tid < NG && scnt[tid] != 0.f) atomicAdd(&cnt[tid], scnt[tid]);
}

__global__ void zero_out_kernel(unsigned short* out, int n16) {
    int i = blockIdx.x * blockDim.x + threadIdx.x;
    if (i < n16) out[i] = 0;
}

extern "C" void kernel_launch(void* const* d_in, const int* in_sizes, int n_in,
                              void* d_out, int out_size, void* d_ws, size_t ws_size,
                              hipStream_t stream) {
    const void* x   = d_in[0];
    const void* ei  = d_in[1];   // [2, E] flat: src then dst
    const void* bat = d_in[2];
    const void* W1  = d_in[3];
    const void* b1  = d_in[4];
    const void* W2  = d_in[5];
    const void* b2  = d_in[6];
    const void* lw  = d_in[7];
    const void* lb  = d_in[8];

    const int N = NNODES, E = NEDGES;
    int* ws = (int*)d_ws;

    // ---- CSR-path layout (words). staging aliases bufA (dead before GEMM1). ----
    const long long o_flags = 0;                          // 16
    const long long o_deg   = 16;                         // N
    const long long o_dinv  = 16 + (long long)N;          // N
    const long long o_rs    = 16 + 2LL * N;               // N+1
    const long long o_bcnt  = 300032;                     // PB*NBUCK+1 = 50177
    const long long o_pool  = 350272;                     // NG*64
    const long long o_cnt   = o_pool + NG * 64;           // NG
    const long long o_csr   = 354432;                     // E
    const long long o_bufA  = o_csr + E;                  // N*64 (= 2E words: staging fits)
    const long long o_bufB  = o_bufA + (long long)N * 64; // N*64
    const size_t need_csr = (size_t)(o_bufB + (long long)N * 64) * 4;   // ~65.4 MB

    // ---- fallback layout ----
    const size_t need_fb = (size_t)(204800 + 2LL * N * 64) * 4;

    if (ws_size >= need_csr) {
        int*   flags   = ws + o_flags;
        int*   deg     = ws + o_deg;
        float* dinv    = (float*)(ws + o_dinv);
        int*   rs      = ws + o_rs;
        int*   bcnt    = ws + o_bcnt;
        float* pooled  = (float*)(ws + o_pool);
        float* cnt     = (float*)(ws + o_cnt);
        int*   csr     = ws + o_csr;
        float* bufA    = (float*)(ws + o_bufA);
        float* bufB    = (float*)(ws + o_bufB);
        uint2* staging = (uint2*)(ws + o_bufA);           // alias: dead before GEMM1

        detect_kernel<<<1, 64, 0, stream>>>(x, ei, bat, flags);
        hipMemsetAsync(pooled, 0, (NG * 64 + NG) * sizeof(float), stream);

        // binned CSR build (no global atomics, dense writes)
        binA_count<<<PB, 256, 0, stream>>>(ei, flags, bcnt, E);
        binA_scan<<<1, 1024, 0, stream>>>(bcnt);
        binA_write<<<PB, 256, 0, stream>>>(ei, flags, bcnt, staging, E);
        binB_deg<<<NBUCK, 256, 0, stream>>>(staging, bcnt, deg);
        dinv_kernel<<<(N + 255) / 256, 256, 0, stream>>>(deg, dinv, N);
        scan_kernel<<<1, 1024, 0, stream>>>(deg, rs, N);
        binB_fill<<<NBUCK, 256, 0, stream>>>(staging, bcnt, rs, csr);

        // layer 1 (GEMM outputs pre-scaled by dinv[row])
        gemm_lds<128, 0><<<1024, 256, 0, stream>>>(x, W1, flags, dinv, bufA, N);
        gather_kernel<<<(N + 3) / 4, 256, 0, stream>>>(bufA, rs, csr, dinv, b1, flags, bufB, N);
        // layer 2
        gemm_lds<64, 1><<<1024, 256, 0, stream>>>(bufB, W2, flags, dinv, bufA, N);
        gather_kernel<<<(N + 3) / 4, 256, 0, stream>>>(bufA, rs, csr, dinv, b2, flags, bufB, N);

        pool2_kernel<<<512, 256, 0, stream>>>(bufB, bat, flags, pooled, cnt, N);
        final_kernel<<<1, 64, 0, stream>>>(pooled, cnt, lw, lb, flags, d_out);
    } else if (ws_size >= need_fb) {
        int*   flags  = ws;
        int*   deg    = ws + 16;
        float* dinv   = (float*)(ws + 16 + N);
        float* pooled = (float*)(ws + 16 + 2LL * N);
        float* cnt    = pooled + NG * 64;
        float* bufA   = (float*)(ws + 204800);
        float* bufB   = bufA + (long long)N * 64;

        detect_kernel<<<1, 64, 0, stream>>>(x, ei, bat, flags);
        hipMemsetAsync(deg, 0, N * sizeof(int), stream);
        hipMemsetAsync(pooled, 0, (NG * 64 + NG) * sizeof(float), stream);

        count_kernel<<<2048, 256, 0, stream>>>(ei, flags, deg, E);
        dinv_kernel<<<(N + 255) / 256, 256, 0, stream>>>(deg, dinv, N);

        gemm_lds<128, 0><<<1024, 256, 0, stream>>>(x, W1, flags, nullptr, bufA, N);
        hipMemsetAsync(bufB, 0, (size_t)N * 64 * sizeof(float), stream);
        scatter_kernel<<<(E + 3) / 4, 256, 0, stream>>>(bufA, ei, flags, dinv, bufB, E);
        relu_bias_kernel<<<((long long)N * 64 + 255) / 256, 256, 0, stream>>>(bufA, bufB, dinv, b1, flags, N);

        gemm_lds<64, 1><<<1024, 256, 0, stream>>>(bufA, W2, flags, nullptr, bufB, N);
        hipMemsetAsync(bufA, 0, (size_t)N * 64 * sizeof(float), stream);
        scatter_kernel<<<(E + 3) / 4, 256, 0, stream>>>(bufB, ei, flags, dinv, bufA, E);

        pool_fb_kernel<<<512, 256, 0, stream>>>(bufA, bufB, dinv, b2, bat, flags, pooled, cnt, N);
        final_kernel<<<1, 64, 0, stream>>>(pooled, cnt, lw, lb, flags, d_out);
    } else {
        zero_out_kernel<<<(out_size * 2 + 255) / 256, 256, 0, stream>>>(
            (unsigned short*)d_out, out_size);
    }
}

// Round 6
// 1551.181 us; speedup vs baseline: 1.0145x; 1.0145x over previous
//
#include <hip/hip_runtime.h>
#include <hip/hip_bf16.h>

#define NNODES 100000
#define NEDGES 3200000
#define NG     64
#define NBUCK  196          // ceil(NNODES/512) buckets of 512 dst nodes
#define PB     256          // phase-A partition blocks

// ---------- dtype-flexible loads (flags are wave-uniform) ----------
__device__ __forceinline__ int ld_idx(const void* p, long long i, int is64) {
    if (is64) return (int)((const long long*)p)[i];
    return ((const int*)p)[i];
}
__device__ __forceinline__ float ld_f(const void* p, long long i, int isf32) {
    if (isf32) return ((const float*)p)[i];
    return __bfloat162float(((const __hip_bfloat16*)p)[i]);
}
__device__ __forceinline__ float bfbits(unsigned b) {
    return __uint_as_float(b << 16);
}

// ---------- runtime dtype detection (proven) ----------
__global__ void detect_kernel(const void* x, const void* ei, const void* bat, int* flags) {
    if (threadIdx.x != 0 || blockIdx.x != 0) return;
    const unsigned short* u = (const unsigned short*)x;
    int isf32 = 0;
    for (int i = 0; i < 256; ++i) {
        int e = (u[i] >> 7) & 0xFF;
        if (e >= 0x90) { isf32 = 1; break; }
    }
    const unsigned* w = (const unsigned*)ei;
    int ei64 = 1;
    for (int j = 1; j < 256; j += 2) if (w[j] != 0u) { ei64 = 0; break; }
    const unsigned* bw = (const unsigned*)bat;
    int b64 = 1;
    for (int j = 50001; j < 50001 + 256; j += 2) if (bw[j] != 0u) { b64 = 0; break; }
    flags[0] = isf32; flags[1] = ei64; flags[2] = b64;
}

// ---------- phase A1: per-(bucket,block) edge counts (LDS only) ----------
__global__ void binA_count(const void* ei, const int* __restrict__ flags,
                           int* __restrict__ bcnt, int E) {
    __shared__ int cnt[NBUCK];
    int is64 = flags[1];
    for (int i = threadIdx.x; i < NBUCK; i += 256) cnt[i] = 0;
    __syncthreads();
    const int chunk = (E + PB - 1) / PB;
    int beg = blockIdx.x * chunk, end = min(E, beg + chunk);
    for (int i = beg + threadIdx.x; i < end; i += 256) {
        int s = ld_idx(ei, i, is64);
        int d = ld_idx(ei, (long long)E + i, is64);
        if ((unsigned)s < (unsigned)NNODES && (unsigned)d < (unsigned)NNODES)
            atomicAdd(&cnt[d >> 9], 1);
    }
    __syncthreads();
    for (int i = threadIdx.x; i < NBUCK; i += 256)
        bcnt[i * PB + blockIdx.x] = cnt[i];     // bucket-major for scan
}

// ---------- phase A2: exclusive scan over PB*NBUCK counts (in place) ----------
__global__ void binA_scan(int* __restrict__ bcnt) {
    __shared__ int ls[1024];
    const int M = PB * NBUCK;
    const int CH = (M + 1023) / 1024;
    int t = threadIdx.x;
    int beg = t * CH, end = min(M, beg + CH);
    int sum = 0;
    for (int i = beg; i < end; ++i) sum += bcnt[i];
    ls[t] = sum;
    __syncthreads();
    for (int off = 1; off < 1024; off <<= 1) {
        int v = (t >= off) ? ls[t - off] : 0;
        __syncthreads();
        ls[t] += v;
        __syncthreads();
    }
    int run = ls[t] - sum;
    for (int i = beg; i < end; ++i) {
        int c = bcnt[i];
        bcnt[i] = run;
        run += c;
    }
    if (t == 1023) bcnt[M] = ls[1023];
}

// ---------- phase A3: partition edges into bucket-ordered staging (s,d) ----------
__global__ void binA_write(const void* ei, const int* __restrict__ flags,
                           const int* __restrict__ bcnt, uint2* __restrict__ staging, int E) {
    __shared__ int cur[NBUCK];
    int is64 = flags[1];
    for (int i = threadIdx.x; i < NBUCK; i += 256) cur[i] = bcnt[i * PB + blockIdx.x];
    __syncthreads();
    const int chunk = (E + PB - 1) / PB;
    int beg = blockIdx.x * chunk, end = min(E, beg + chunk);
    for (int i = beg + threadIdx.x; i < end; i += 256) {
        int s = ld_idx(ei, i, is64);
        int d = ld_idx(ei, (long long)E + i, is64);
        if ((unsigned)s < (unsigned)NNODES && (unsigned)d < (unsigned)NNODES) {
            int pos = atomicAdd(&cur[d >> 9], 1);
            staging[pos] = make_uint2((unsigned)s, (unsigned)d);
        }
    }
}

// ---------- phase B1: per-bucket node degrees (LDS counters) ----------
__global__ void binB_deg(const uint2* __restrict__ staging, const int* __restrict__ bcnt,
                         int* __restrict__ deg) {
    __shared__ int dcnt[512];
    int b = blockIdx.x;
    int lo = b << 9;
    for (int i = threadIdx.x; i < 512; i += 256) dcnt[i] = 0;
    __syncthreads();
    int beg = bcnt[b * PB], end = bcnt[(b + 1) * PB];
    for (int i = beg + threadIdx.x; i < end; i += 256)
        atomicAdd(&dcnt[staging[i].y - lo], 1);
    __syncthreads();
    for (int i = threadIdx.x; i < 512; i += 256)
        if (lo + i < NNODES) deg[lo + i] = dcnt[i];
}

__global__ void dinv_kernel(const int* __restrict__ deg, float* __restrict__ dinv, int N) {
    int i = blockIdx.x * blockDim.x + threadIdx.x;
    if (i < N) dinv[i] = rsqrtf((float)deg[i] + 1.0f);   // +1 = self-loop
}

// ---------- exclusive scan deg -> row_start ----------
__global__ void scan_kernel(int* __restrict__ deg, int* __restrict__ row_start, int N) {
    __shared__ int ls[1024];
    const int CH = (N + 1023) / 1024;
    int t = threadIdx.x;
    int beg = t * CH, end = min(N, beg + CH);
    int sum = 0;
    for (int i = beg; i < end; ++i) sum += deg[i];
    ls[t] = sum;
    __syncthreads();
    for (int off = 1; off < 1024; off <<= 1) {
        int v = (t >= off) ? ls[t - off] : 0;
        __syncthreads();
        ls[t] += v;
        __syncthreads();
    }
    int run = ls[t] - sum;
    for (int i = beg; i < end; ++i) {
        row_start[i] = run;
        run += deg[i];
    }
    if (t == 1023) row_start[N] = ls[1023];
}

// ---------- phase B2: per-bucket CSR fill (LDS cursors; dense 65KB write regions) ----------
__global__ void binB_fill(const uint2* __restrict__ staging, const int* __restrict__ bcnt,
                          const int* __restrict__ rs, int* __restrict__ csr) {
    __shared__ int cur[512];
    int b = blockIdx.x;
    int lo = b << 9;
    for (int i = threadIdx.x; i < 512; i += 256)
        cur[i] = (lo + i < NNODES) ? rs[lo + i] : 0;
    __syncthreads();
    int beg = bcnt[b * PB], end = bcnt[(b + 1) * PB];
    for (int i = beg + threadIdx.x; i < end; i += 256) {
        uint2 u = staging[i];
        int pos = atomicAdd(&cur[u.y - lo], 1);
        csr[pos] = (int)u.x;
    }
}

// ---------- GEMM: W in LDS, 4 rows/wave; __launch_bounds__(256,4) -> 128 VGPR, no spill ----------
// SRC==0: X has detected dtype; SRC==1: X is fp32 workspace
template <int K, int SRC>
__global__ __launch_bounds__(256, 4)
void gemm_lds(const void* __restrict__ X, const void* __restrict__ W,
              const int* __restrict__ flags, const float* __restrict__ dscale,
              float* __restrict__ Out, int N) {
    __shared__ float lsW[K * 64];
    int isf32 = flags[0];
    for (int i = threadIdx.x; i < K * 64; i += 256) lsW[i] = ld_f(W, i, isf32);
    __syncthreads();

    int c = threadIdx.x & 63;
    int wave = blockIdx.x * 4 + (threadIdx.x >> 6);
    int nwaves = gridDim.x * 4;
    int ngroups = (N + 3) >> 2;

    for (int g = wave; g < ngroups; g += nwaves) {
        int base = g * 4;
        float acc0 = 0.f, acc1 = 0.f, acc2 = 0.f, acc3 = 0.f;
        if (base + 3 < N) {
            if (SRC == 1 || isf32) {
                const float4* x0 = (const float4*)((const float*)X + (long long)(base + 0) * K);
                const float4* x1 = (const float4*)((const float*)X + (long long)(base + 1) * K);
                const float4* x2 = (const float4*)((const float*)X + (long long)(base + 2) * K);
                const float4* x3 = (const float4*)((const float*)X + (long long)(base + 3) * K);
#pragma unroll
                for (int k4 = 0; k4 < K / 4; ++k4) {
                    float4 a0 = x0[k4], a1 = x1[k4], a2 = x2[k4], a3 = x3[k4];
                    float w0 = lsW[(4 * k4 + 0) * 64 + c];
                    float w1 = lsW[(4 * k4 + 1) * 64 + c];
                    float w2 = lsW[(4 * k4 + 2) * 64 + c];
                    float w3 = lsW[(4 * k4 + 3) * 64 + c];
                    acc0 += a0.x * w0 + a0.y * w1 + a0.z * w2 + a0.w * w3;
                    acc1 += a1.x * w0 + a1.y * w1 + a1.z * w2 + a1.w * w3;
                    acc2 += a2.x * w0 + a2.y * w1 + a2.z * w2 + a2.w * w3;
                    acc3 += a3.x * w0 + a3.y * w1 + a3.z * w2 + a3.w * w3;
                }
            } else {
                const uint2* x0 = (const uint2*)((const unsigned short*)X + (long long)(base + 0) * K);
                const uint2* x1 = (const uint2*)((const unsigned short*)X + (long long)(base + 1) * K);
                const uint2* x2 = (const uint2*)((const unsigned short*)X + (long long)(base + 2) * K);
                const uint2* x3 = (const uint2*)((const unsigned short*)X + (long long)(base + 3) * K);
#pragma unroll
                for (int k4 = 0; k4 < K / 4; ++k4) {
                    uint2 u0 = x0[k4], u1 = x1[k4], u2 = x2[k4], u3 = x3[k4];
                    float w0 = lsW[(4 * k4 + 0) * 64 + c];
                    float w1 = lsW[(4 * k4 + 1) * 64 + c];
                    float w2 = lsW[(4 * k4 + 2) * 64 + c];
                    float w3 = lsW[(4 * k4 + 3) * 64 + c];
                    acc0 += bfbits(u0.x & 0xffffu) * w0 + bfbits(u0.x >> 16) * w1
                          + bfbits(u0.y & 0xffffu) * w2 + bfbits(u0.y >> 16) * w3;
                    acc1 += bfbits(u1.x & 0xffffu) * w0 + bfbits(u1.x >> 16) * w1
                          + bfbits(u1.y & 0xffffu) * w2 + bfbits(u1.y >> 16) * w3;
                    acc2 += bfbits(u2.x & 0xffffu) * w0 + bfbits(u2.x >> 16) * w1
                          + bfbits(u2.y & 0xffffu) * w2 + bfbits(u2.y >> 16) * w3;
                    acc3 += bfbits(u3.x & 0xffffu) * w0 + bfbits(u3.x >> 16) * w1
                          + bfbits(u3.y & 0xffffu) * w2 + bfbits(u3.y >> 16) * w3;
                }
            }
            float d0 = 1.f, d1 = 1.f, d2 = 1.f, d3 = 1.f;
            if (dscale) { d0 = dscale[base]; d1 = dscale[base + 1]; d2 = dscale[base + 2]; d3 = dscale[base + 3]; }
            Out[(long long)(base + 0) * 64 + c] = acc0 * d0;
            Out[(long long)(base + 1) * 64 + c] = acc1 * d1;
            Out[(long long)(base + 2) * 64 + c] = acc2 * d2;
            Out[(long long)(base + 3) * 64 + c] = acc3 * d3;
        } else {
            for (int r = base; r < N; ++r) {
                float s = 0.f;
                for (int k = 0; k < K; ++k) {
                    float xv = (SRC == 1) ? ((const float*)X)[(long long)r * K + k]
                                          : ld_f(X, (long long)r * K + k, isf32);
                    s += xv * lsW[k * 64 + c];
                }
                if (dscale) s *= dscale[r];
                Out[(long long)r * 64 + c] = s;
            }
        }
    }
}

// ---------- CSR gather over pre-scaled Hs; optional output pre-scale for next layer ----------
// out_scale != nullptr: Hout = relu(...) * out_scale[n]  (row-scale commutes with X@W)
__global__ void gather_kernel(const float* __restrict__ Hs,
                              const int* __restrict__ row_start,
                              const int* __restrict__ csr_src,
                              const float* __restrict__ dinv,
                              const void* bias, const int* __restrict__ flags,
                              const float* __restrict__ out_scale,
                              float* __restrict__ Hout, int N) {
    int isf32 = flags[0];
    int c = threadIdx.x & 63;
    int n = blockIdx.x * 4 + (threadIdx.x >> 6);
    if (n >= N) return;
    int beg = row_start[n], end = row_start[n + 1];
    float a0 = Hs[(long long)n * 64 + c];     // self-loop term (already ×dinv[n])
    float a1 = 0.f;
    int i = beg;
    for (; i + 3 < end; i += 4) {
        int s0 = csr_src[i], s1 = csr_src[i + 1], s2 = csr_src[i + 2], s3 = csr_src[i + 3];
        float h0 = Hs[(long long)s0 * 64 + c];
        float h1 = Hs[(long long)s1 * 64 + c];
        float h2 = Hs[(long long)s2 * 64 + c];
        float h3 = Hs[(long long)s3 * 64 + c];
        a0 += h0 + h2;
        a1 += h1 + h3;
    }
    for (; i < end; ++i)
        a0 += Hs[(long long)csr_src[i] * 64 + c];
    float v = (a0 + a1) * dinv[n] + ld_f(bias, c, isf32);
    float r = v > 0.f ? v : 0.f;
    if (out_scale) r *= out_scale[n];
    Hout[(long long)n * 64 + c] = r;
}

// ---------- pooling over final H ----------
__global__ void pool2_kernel(const float* __restrict__ H, const void* batch,
                             const int* __restrict__ flags,
                             float* __restrict__ pooled, float* __restrict__ cnt, int N) {
    __shared__ float part[NG * 64];
    __shared__ float scnt[NG];
    int b64 = flags[2];
    int tid = threadIdx.x;
    for (int i = tid; i < NG * 64; i += blockDim.x) part[i] = 0.f;
    if (tid < NG) scnt[tid] = 0.f;
    __syncthreads();
    int c = tid & 63;
    int sub = tid >> 6;
    for (int n = blockIdx.x * 4 + sub; n < N; n += gridDim.x * 4) {
        int g = ld_idx(batch, n, b64);
        if ((unsigned)g >= (unsigned)NG) continue;
        atomicAdd(&part[g * 64 + c], H[(long long)n * 64 + c]);
        if (c == 0) atomicAdd(&scnt[g], 1.0f);
    }
    __syncthreads();
    for (int i = tid; i < NG * 64; i += blockDim.x) {
        float v = part[i];
        if (v != 0.f) atomicAdd(&pooled[i], v);
    }
    if (tid < NG && scnt[tid] != 0.f) atomicAdd(&cnt[tid], scnt[tid]);
}

// ---------- final ----------
__global__ void final_kernel(const float* __restrict__ pooled, const float* __restrict__ cnt,
                             const void* lw, const void* lb,
                             const int* __restrict__ flags, void* out) {
    int isf32 = flags[0];
    int g = threadIdx.x;
    if (g >= NG) return;
    float inv = 1.0f / fmaxf(cnt[g], 1.0f);
    float logits[10];
    for (int c = 0; c < 10; ++c) logits[c] = ld_f(lb, c, isf32);
    for (int k = 0; k < 64; ++k) {
        float m = pooled[g * 64 + k] * inv;
        for (int c = 0; c < 10; ++c)
            logits[c] += m * ld_f(lw, k * 10 + c, isf32);
    }
    float mx = logits[0];
    for (int c = 1; c < 10; ++c) mx = fmaxf(mx, logits[c]);
    float se = 0.f;
    for (int c = 0; c < 10; ++c) se += __expf(logits[c] - mx);
    float lse = mx + __logf(se);
    if (isf32) {
        float* o = (float*)out;
        for (int c = 0; c < 10; ++c) o[g * 10 + c] = logits[c] - lse;
    } else {
        __hip_bfloat16* o = (__hip_bfloat16*)out;
        for (int c = 0; c < 10; ++c) o[g * 10 + c] = __float2bfloat16(logits[c] - lse);
    }
}

// ---------- fallback pipeline kernels (round-2 proven, atomic scatter) ----------
__global__ void count_kernel(const void* ei, const int* __restrict__ flags,
                             int* __restrict__ deg, int E) {
    int is64 = flags[1];
    int i = blockIdx.x * blockDim.x + threadIdx.x;
    int stride = gridDim.x * blockDim.x;
    for (; i < E; i += stride) {
        int d = ld_idx(ei, (long long)E + i, is64);
        if ((unsigned)d < (unsigned)NNODES) atomicAdd(&deg[d], 1);
    }
}

__global__ void scatter_kernel(const float* __restrict__ H, const void* ei,
                               const int* __restrict__ flags,
                               const float* __restrict__ dinv,
                               float* __restrict__ agg, int E) {
    int is64 = flags[1];
    int lane = threadIdx.x & 63;
    int e = blockIdx.x * 4 + (threadIdx.x >> 6);
    if (e >= E) return;
    int s = ld_idx(ei, e, is64);
    int d = ld_idx(ei, (long long)E + e, is64);
    if ((unsigned)s >= (unsigned)NNODES || (unsigned)d >= (unsigned)NNODES) return;
    float nrm = dinv[s] * dinv[d];
    float v = H[(long long)s * 64 + lane] * nrm;
    atomicAdd(&agg[(long long)d * 64 + lane], v);
}

__global__ void relu_bias_kernel(float* __restrict__ H, const float* __restrict__ agg,
                                 const float* __restrict__ dinv, const void* b,
                                 const int* __restrict__ flags, int N) {
    int isf32 = flags[0];
    long long idx = (long long)blockIdx.x * blockDim.x + threadIdx.x;
    if (idx >= (long long)N * 64) return;
    int n = (int)(idx >> 6);
    int c = (int)(idx & 63);
    float dv = dinv[n];
    float v = agg[idx] + H[idx] * dv * dv + ld_f(b, c, isf32);
    H[idx] = v > 0.f ? v : 0.f;
}

__global__ void pool_fb_kernel(const float* __restrict__ agg, const float* __restrict__ Hg,
                               const float* __restrict__ dinv, const void* b,
                               const void* batch, const int* __restrict__ flags,
                               float* __restrict__ pooled, float* __restrict__ cnt, int N) {
    __shared__ float part[NG * 64];
    __shared__ float scnt[NG];
    int isf32 = flags[0];
    int b64   = flags[2];
    int tid = threadIdx.x;
    for (int i = tid; i < NG * 64; i += blockDim.x) part[i] = 0.f;
    if (tid < NG) scnt[tid] = 0.f;
    __syncthreads();
    int c = tid & 63;
    int sub = tid >> 6;
    float bc = ld_f(b, c, isf32);
    for (int n = blockIdx.x * 4 + sub; n < N; n += gridDim.x * 4) {
        int g = ld_idx(batch, n, b64);
        if ((unsigned)g >= (unsigned)NG) continue;
        float dv = dinv[n];
        float v = agg[(long long)n * 64 + c] + Hg[(long long)n * 64 + c] * dv * dv + bc;
        v = v > 0.f ? v : 0.f;
        atomicAdd(&part[g * 64 + c], v);
        if (c == 0) atomicAdd(&scnt[g], 1.0f);
    }
    __syncthreads();
    for (int i = tid; i < NG * 64; i += blockDim.x) {
        float v = part[i];
        if (v != 0.f) atomicAdd(&pooled[i], v);
    }
    if (tid < NG && scnt[tid] != 0.f) atomicAdd(&cnt[tid], scnt[tid]);
}

__global__ void zero_out_kernel(unsigned short* out, int n16) {
    int i = blockIdx.x * blockDim.x + threadIdx.x;
    if (i < n16) out[i] = 0;
}

extern "C" void kernel_launch(void* const* d_in, const int* in_sizes, int n_in,
                              void* d_out, int out_size, void* d_ws, size_t ws_size,
                              hipStream_t stream) {
    const void* x   = d_in[0];
    const void* ei  = d_in[1];   // [2, E] flat: src then dst
    const void* bat = d_in[2];
    const void* W1  = d_in[3];
    const void* b1  = d_in[4];
    const void* W2  = d_in[5];
    const void* b2  = d_in[6];
    const void* lw  = d_in[7];
    const void* lb  = d_in[8];

    const int N = NNODES, E = NEDGES;
    int* ws = (int*)d_ws;

    // ---- CSR-path layout (words). staging aliases bufA (dead before GEMM1). ----
    const long long o_flags = 0;                          // 16
    const long long o_deg   = 16;                         // N
    const long long o_dinv  = 16 + (long long)N;          // N
    const long long o_rs    = 16 + 2LL * N;               // N+1
    const long long o_bcnt  = 300032;                     // PB*NBUCK+1 = 50177
    const long long o_pool  = 350272;                     // NG*64
    const long long o_cnt   = o_pool + NG * 64;           // NG
    const long long o_csr   = 354432;                     // E
    const long long o_bufA  = o_csr + E;                  // N*64 (= 2E words: staging fits)
    const long long o_bufB  = o_bufA + (long long)N * 64; // N*64
    const size_t need_csr = (size_t)(o_bufB + (long long)N * 64) * 4;   // ~65.4 MB

    // ---- fallback layout ----
    const size_t need_fb = (size_t)(204800 + 2LL * N * 64) * 4;

    if (ws_size >= need_csr) {
        int*   flags   = ws + o_flags;
        int*   deg     = ws + o_deg;
        float* dinv    = (float*)(ws + o_dinv);
        int*   rs      = ws + o_rs;
        int*   bcnt    = ws + o_bcnt;
        float* pooled  = (float*)(ws + o_pool);
        float* cnt     = (float*)(ws + o_cnt);
        int*   csr     = ws + o_csr;
        float* bufA    = (float*)(ws + o_bufA);
        float* bufB    = (float*)(ws + o_bufB);
        uint2* staging = (uint2*)(ws + o_bufA);           // alias: dead before GEMM1

        detect_kernel<<<1, 64, 0, stream>>>(x, ei, bat, flags);
        hipMemsetAsync(pooled, 0, (NG * 64 + NG) * sizeof(float), stream);

        // binned CSR build (no global atomics, dense writes)
        binA_count<<<PB, 256, 0, stream>>>(ei, flags, bcnt, E);
        binA_scan<<<1, 1024, 0, stream>>>(bcnt);
        binA_write<<<PB, 256, 0, stream>>>(ei, flags, bcnt, staging, E);
        binB_deg<<<NBUCK, 256, 0, stream>>>(staging, bcnt, deg);
        dinv_kernel<<<(N + 255) / 256, 256, 0, stream>>>(deg, dinv, N);
        scan_kernel<<<1, 1024, 0, stream>>>(deg, rs, N);
        binB_fill<<<NBUCK, 256, 0, stream>>>(staging, bcnt, rs, csr);

        // layer 1: gemm1 outputs dinv[row]*(x@W1); gather1 outputs dinv[row]*relu(...)
        gemm_lds<128, 0><<<1024, 256, 0, stream>>>(x, W1, flags, dinv, bufA, N);
        gather_kernel<<<(N + 3) / 4, 256, 0, stream>>>(bufA, rs, csr, dinv, b1, flags, dinv, bufB, N);
        // layer 2: row-scale already folded into bufB -> gemm2 needs no dscale
        gemm_lds<64, 1><<<1024, 256, 0, stream>>>(bufB, W2, flags, nullptr, bufA, N);
        gather_kernel<<<(N + 3) / 4, 256, 0, stream>>>(bufA, rs, csr, dinv, b2, flags, nullptr, bufB, N);

        pool2_kernel<<<512, 256, 0, stream>>>(bufB, bat, flags, pooled, cnt, N);
        final_kernel<<<1, 64, 0, stream>>>(pooled, cnt, lw, lb, flags, d_out);
    } else if (ws_size >= need_fb) {
        int*   flags  = ws;
        int*   deg    = ws + 16;
        float* dinv   = (float*)(ws + 16 + N);
        float* pooled = (float*)(ws + 16 + 2LL * N);
        float* cnt    = pooled + NG * 64;
        float* bufA   = (float*)(ws + 204800);
        float* bufB   = bufA + (long long)N * 64;

        detect_kernel<<<1, 64, 0, stream>>>(x, ei, bat, flags);
        hipMemsetAsync(deg, 0, N * sizeof(int), stream);
        hipMemsetAsync(pooled, 0, (NG * 64 + NG) * sizeof(float), stream);

        count_kernel<<<2048, 256, 0, stream>>>(ei, flags, deg, E);
        dinv_kernel<<<(N + 255) / 256, 256, 0, stream>>>(deg, dinv, N);

        gemm_lds<128, 0><<<1024, 256, 0, stream>>>(x, W1, flags, nullptr, bufA, N);
        hipMemsetAsync(bufB, 0, (size_t)N * 64 * sizeof(float), stream);
        scatter_kernel<<<(E + 3) / 4, 256, 0, stream>>>(bufA, ei, flags, dinv, bufB, E);
        relu_bias_kernel<<<((long long)N * 64 + 255) / 256, 256, 0, stream>>>(bufA, bufB, dinv, b1, flags, N);

        gemm_lds<64, 1><<<1024, 256, 0, stream>>>(bufA, W2, flags, nullptr, bufB, N);
        hipMemsetAsync(bufA, 0, (size_t)N * 64 * sizeof(float), stream);
        scatter_kernel<<<(E + 3) / 4, 256, 0, stream>>>(bufB, ei, flags, dinv, bufA, E);

        pool_fb_kernel<<<512, 256, 0, stream>>>(bufA, bufB, dinv, b2, bat, flags, pooled, cnt, N);
        final_kernel<<<1, 64, 0, stream>>>(pooled, cnt, lw, lb, flags, d_out);
    } else {
        zero_out_kernel<<<(out_size * 2 + 255) / 256, 256, 0, stream>>>(
            (unsigned short*)d_out, out_size);
    }
}

// Round 7
// 820.862 us; speedup vs baseline: 1.9171x; 1.8897x over previous
//
#include <hip/hip_runtime.h>
#include <hip/hip_bf16.h>

#define NNODES 100000
#define NEDGES 3200000
#define NG     64
#define NBUCK  196          // ceil(NNODES/512) buckets of 512 dst nodes
#define PB     256          // phase-A partition blocks

// ---------- dtype-flexible loads (flags are wave-uniform) ----------
__device__ __forceinline__ int ld_idx(const void* p, long long i, int is64) {
    if (is64) return (int)((const long long*)p)[i];
    return ((const int*)p)[i];
}
__device__ __forceinline__ float ld_f(const void* p, long long i, int isf32) {
    if (isf32) return ((const float*)p)[i];
    return __bfloat162float(((const __hip_bfloat16*)p)[i]);
}
__device__ __forceinline__ float bfbits(unsigned b) {
    return __uint_as_float(b << 16);
}

// ---------- runtime dtype detection (proven) ----------
__global__ void detect_kernel(const void* x, const void* ei, const void* bat, int* flags) {
    if (threadIdx.x != 0 || blockIdx.x != 0) return;
    const unsigned short* u = (const unsigned short*)x;
    int isf32 = 0;
    for (int i = 0; i < 256; ++i) {
        int e = (u[i] >> 7) & 0xFF;
        if (e >= 0x90) { isf32 = 1; break; }
    }
    const unsigned* w = (const unsigned*)ei;
    int ei64 = 1;
    for (int j = 1; j < 256; j += 2) if (w[j] != 0u) { ei64 = 0; break; }
    const unsigned* bw = (const unsigned*)bat;
    int b64 = 1;
    for (int j = 50001; j < 50001 + 256; j += 2) if (bw[j] != 0u) { b64 = 0; break; }
    flags[0] = isf32; flags[1] = ei64; flags[2] = b64;
}

// ---------- phase A1: per-(bucket,block) edge counts (LDS only) ----------
__global__ void binA_count(const void* ei, const int* __restrict__ flags,
                           int* __restrict__ bcnt, int E) {
    __shared__ int cnt[NBUCK];
    int is64 = flags[1];
    for (int i = threadIdx.x; i < NBUCK; i += 256) cnt[i] = 0;
    __syncthreads();
    const int chunk = (E + PB - 1) / PB;
    int beg = blockIdx.x * chunk, end = min(E, beg + chunk);
    for (int i = beg + threadIdx.x; i < end; i += 256) {
        int s = ld_idx(ei, i, is64);
        int d = ld_idx(ei, (long long)E + i, is64);
        if ((unsigned)s < (unsigned)NNODES && (unsigned)d < (unsigned)NNODES)
            atomicAdd(&cnt[d >> 9], 1);
    }
    __syncthreads();
    for (int i = threadIdx.x; i < NBUCK; i += 256)
        bcnt[i * PB + blockIdx.x] = cnt[i];     // bucket-major for scan
}

// ---------- phase A2: exclusive scan over PB*NBUCK counts (in place) ----------
__global__ void binA_scan(int* __restrict__ bcnt) {
    __shared__ int ls[1024];
    const int M = PB * NBUCK;
    const int CH = (M + 1023) / 1024;
    int t = threadIdx.x;
    int beg = t * CH, end = min(M, beg + CH);
    int sum = 0;
    for (int i = beg; i < end; ++i) sum += bcnt[i];
    ls[t] = sum;
    __syncthreads();
    for (int off = 1; off < 1024; off <<= 1) {
        int v = (t >= off) ? ls[t - off] : 0;
        __syncthreads();
        ls[t] += v;
        __syncthreads();
    }
    int run = ls[t] - sum;
    for (int i = beg; i < end; ++i) {
        int c = bcnt[i];
        bcnt[i] = run;
        run += c;
    }
    if (t == 1023) bcnt[M] = ls[1023];
}

// ---------- phase A3: partition edges into bucket-ordered staging (s,d) ----------
__global__ void binA_write(const void* ei, const int* __restrict__ flags,
                           const int* __restrict__ bcnt, uint2* __restrict__ staging, int E) {
    __shared__ int cur[NBUCK];
    int is64 = flags[1];
    for (int i = threadIdx.x; i < NBUCK; i += 256) cur[i] = bcnt[i * PB + blockIdx.x];
    __syncthreads();
    const int chunk = (E + PB - 1) / PB;
    int beg = blockIdx.x * chunk, end = min(E, beg + chunk);
    for (int i = beg + threadIdx.x; i < end; i += 256) {
        int s = ld_idx(ei, i, is64);
        int d = ld_idx(ei, (long long)E + i, is64);
        if ((unsigned)s < (unsigned)NNODES && (unsigned)d < (unsigned)NNODES) {
            int pos = atomicAdd(&cur[d >> 9], 1);
            staging[pos] = make_uint2((unsigned)s, (unsigned)d);
        }
    }
}

// ---------- phase B1: per-bucket node degrees (LDS counters) ----------
__global__ void binB_deg(const uint2* __restrict__ staging, const int* __restrict__ bcnt,
                         int* __restrict__ deg) {
    __shared__ int dcnt[512];
    int b = blockIdx.x;
    int lo = b << 9;
    for (int i = threadIdx.x; i < 512; i += 256) dcnt[i] = 0;
    __syncthreads();
    int beg = bcnt[b * PB], end = bcnt[(b + 1) * PB];
    for (int i = beg + threadIdx.x; i < end; i += 256)
        atomicAdd(&dcnt[staging[i].y - lo], 1);
    __syncthreads();
    for (int i = threadIdx.x; i < 512; i += 256)
        if (lo + i < NNODES) deg[lo + i] = dcnt[i];
}

__global__ void dinv_kernel(const int* __restrict__ deg, float* __restrict__ dinv, int N) {
    int i = blockIdx.x * blockDim.x + threadIdx.x;
    if (i < N) dinv[i] = rsqrtf((float)deg[i] + 1.0f);   // +1 = self-loop
}

// ---------- exclusive scan deg -> row_start ----------
__global__ void scan_kernel(int* __restrict__ deg, int* __restrict__ row_start, int N) {
    __shared__ int ls[1024];
    const int CH = (N + 1023) / 1024;
    int t = threadIdx.x;
    int beg = t * CH, end = min(N, beg + CH);
    int sum = 0;
    for (int i = beg; i < end; ++i) sum += deg[i];
    ls[t] = sum;
    __syncthreads();
    for (int off = 1; off < 1024; off <<= 1) {
        int v = (t >= off) ? ls[t - off] : 0;
        __syncthreads();
        ls[t] += v;
        __syncthreads();
    }
    int run = ls[t] - sum;
    for (int i = beg; i < end; ++i) {
        row_start[i] = run;
        run += deg[i];
    }
    if (t == 1023) row_start[N] = ls[1023];
}

// ---------- phase B2: per-bucket CSR fill (LDS cursors; dense 65KB write regions) ----------
__global__ void binB_fill(const uint2* __restrict__ staging, const int* __restrict__ bcnt,
                          const int* __restrict__ rs, int* __restrict__ csr) {
    __shared__ int cur[512];
    int b = blockIdx.x;
    int lo = b << 9;
    for (int i = threadIdx.x; i < 512; i += 256)
        cur[i] = (lo + i < NNODES) ? rs[lo + i] : 0;
    __syncthreads();
    int beg = bcnt[b * PB], end = bcnt[(b + 1) * PB];
    for (int i = beg + threadIdx.x; i < end; i += 256) {
        uint2 u = staging[i];
        int pos = atomicAdd(&cur[u.y - lo], 1);
        csr[pos] = (int)u.x;
    }
}

// ---------- GEMM: X-tile (64 rows) + W both staged in LDS; coalesced global loads only.
// Each wave owns 16 rows (acc[16]); K chunked by 8 -> live set ~45 VGPR, nothing to spill.
// SRC==0: X has detected dtype; SRC==1: X is fp32 workspace
template <int K, int SRC>
__global__ __launch_bounds__(256)
void gemm_tile(const void* __restrict__ X, const void* __restrict__ W,
               const int* __restrict__ flags, const float* __restrict__ dscale,
               float* __restrict__ Out, int N) {
    __shared__ float lsW[K * 64];     // [k][c]
    __shared__ float lsX[64 * K];     // [r][k], fp32 after conversion
    int isf32 = flags[0];
    for (int i = threadIdx.x; i < K * 64; i += 256) lsW[i] = ld_f(W, i, isf32);

    int c  = threadIdx.x & 63;
    int wv = threadIdx.x >> 6;        // 0..3, wave owns rows [wv*16, wv*16+16)
    int ntiles = (N + 63) >> 6;

    for (int t = blockIdx.x; t < ntiles; t += gridDim.x) {
        int row0 = t << 6;
        int nrows = min(64, N - row0);
        int total = nrows * K;
        __syncthreads();              // prev-tile readers done before overwrite (also covers lsW 1st iter)
        if (SRC == 1 || isf32) {
            const float* Xb = (const float*)X + (long long)row0 * K;
            for (int i = threadIdx.x; i < total; i += 256) lsX[i] = Xb[i];
        } else {
            const unsigned short* Xb = (const unsigned short*)X + (long long)row0 * K;
            for (int i = threadIdx.x; i < total; i += 256) lsX[i] = bfbits((unsigned)Xb[i]);
        }
        __syncthreads();

        int rbase = wv * 16;
        float acc[16];
#pragma unroll
        for (int r = 0; r < 16; ++r) acc[r] = 0.f;
#pragma unroll 1
        for (int kc = 0; kc < K; kc += 8) {
            float w0 = lsW[(kc + 0) * 64 + c], w1 = lsW[(kc + 1) * 64 + c];
            float w2 = lsW[(kc + 2) * 64 + c], w3 = lsW[(kc + 3) * 64 + c];
            float w4 = lsW[(kc + 4) * 64 + c], w5 = lsW[(kc + 5) * 64 + c];
            float w6 = lsW[(kc + 6) * 64 + c], w7 = lsW[(kc + 7) * 64 + c];
#pragma unroll
            for (int r = 0; r < 16; ++r) {
                const float4* xp = (const float4*)&lsX[(rbase + r) * K + kc];
                float4 xa = xp[0], xb = xp[1];   // LDS broadcast reads
                acc[r] += xa.x * w0 + xa.y * w1 + xa.z * w2 + xa.w * w3
                        + xb.x * w4 + xb.y * w5 + xb.z * w6 + xb.w * w7;
            }
        }
        long long ob = (long long)row0 * 64;
#pragma unroll
        for (int r = 0; r < 16; ++r) {
            int rr = rbase + r;
            if (rr < nrows) {
                float v = acc[r];
                if (dscale) v *= dscale[row0 + rr];
                Out[ob + (long long)rr * 64 + c] = v;
            }
        }
    }
}

// ---------- CSR gather over pre-scaled Hs; optional output pre-scale for next layer ----------
__global__ void gather_kernel(const float* __restrict__ Hs,
                              const int* __restrict__ row_start,
                              const int* __restrict__ csr_src,
                              const float* __restrict__ dinv,
                              const void* bias, const int* __restrict__ flags,
                              const float* __restrict__ out_scale,
                              float* __restrict__ Hout, int N) {
    int isf32 = flags[0];
    int c = threadIdx.x & 63;
    int n = blockIdx.x * 4 + (threadIdx.x >> 6);
    if (n >= N) return;
    int beg = row_start[n], end = row_start[n + 1];
    float a0 = Hs[(long long)n * 64 + c];     // self-loop term (already ×dinv[n])
    float a1 = 0.f;
    int i = beg;
    for (; i + 3 < end; i += 4) {
        int s0 = csr_src[i], s1 = csr_src[i + 1], s2 = csr_src[i + 2], s3 = csr_src[i + 3];
        float h0 = Hs[(long long)s0 * 64 + c];
        float h1 = Hs[(long long)s1 * 64 + c];
        float h2 = Hs[(long long)s2 * 64 + c];
        float h3 = Hs[(long long)s3 * 64 + c];
        a0 += h0 + h2;
        a1 += h1 + h3;
    }
    for (; i < end; ++i)
        a0 += Hs[(long long)csr_src[i] * 64 + c];
    float v = (a0 + a1) * dinv[n] + ld_f(bias, c, isf32);
    float r = v > 0.f ? v : 0.f;
    if (out_scale) r *= out_scale[n];
    Hout[(long long)n * 64 + c] = r;
}

// ---------- pooling over final H ----------
__global__ void pool2_kernel(const float* __restrict__ H, const void* batch,
                             const int* __restrict__ flags,
                             float* __restrict__ pooled, float* __restrict__ cnt, int N) {
    __shared__ float part[NG * 64];
    __shared__ float scnt[NG];
    int b64 = flags[2];
    int tid = threadIdx.x;
    for (int i = tid; i < NG * 64; i += blockDim.x) part[i] = 0.f;
    if (tid < NG) scnt[tid] = 0.f;
    __syncthreads();
    int c = tid & 63;
    int sub = tid >> 6;
    for (int n = blockIdx.x * 4 + sub; n < N; n += gridDim.x * 4) {
        int g = ld_idx(batch, n, b64);
        if ((unsigned)g >= (unsigned)NG) continue;
        atomicAdd(&part[g * 64 + c], H[(long long)n * 64 + c]);
        if (c == 0) atomicAdd(&scnt[g], 1.0f);
    }
    __syncthreads();
    for (int i = tid; i < NG * 64; i += blockDim.x) {
        float v = part[i];
        if (v != 0.f) atomicAdd(&pooled[i], v);
    }
    if (tid < NG && scnt[tid] != 0.f) atomicAdd(&cnt[tid], scnt[tid]);
}

// ---------- final ----------
__global__ void final_kernel(const float* __restrict__ pooled, const float* __restrict__ cnt,
                             const void* lw, const void* lb,
                             const int* __restrict__ flags, void* out) {
    int isf32 = flags[0];
    int g = threadIdx.x;
    if (g >= NG) return;
    float inv = 1.0f / fmaxf(cnt[g], 1.0f);
    float logits[10];
    for (int c = 0; c < 10; ++c) logits[c] = ld_f(lb, c, isf32);
    for (int k = 0; k < 64; ++k) {
        float m = pooled[g * 64 + k] * inv;
        for (int c = 0; c < 10; ++c)
            logits[c] += m * ld_f(lw, k * 10 + c, isf32);
    }
    float mx = logits[0];
    for (int c = 1; c < 10; ++c) mx = fmaxf(mx, logits[c]);
    float se = 0.f;
    for (int c = 0; c < 10; ++c) se += __expf(logits[c] - mx);
    float lse = mx + __logf(se);
    if (isf32) {
        float* o = (float*)out;
        for (int c = 0; c < 10; ++c) o[g * 10 + c] = logits[c] - lse;
    } else {
        __hip_bfloat16* o = (__hip_bfloat16*)out;
        for (int c = 0; c < 10; ++c) o[g * 10 + c] = __float2bfloat16(logits[c] - lse);
    }
}

// ---------- fallback pipeline kernels (round-2 proven, atomic scatter) ----------
__global__ void count_kernel(const void* ei, const int* __restrict__ flags,
                             int* __restrict__ deg, int E) {
    int is64 = flags[1];
    int i = blockIdx.x * blockDim.x + threadIdx.x;
    int stride = gridDim.x * blockDim.x;
    for (; i < E; i += stride) {
        int d = ld_idx(ei, (long long)E + i, is64);
        if ((unsigned)d < (unsigned)NNODES) atomicAdd(&deg[d], 1);
    }
}

__global__ void scatter_kernel(const float* __restrict__ H, const void* ei,
                               const int* __restrict__ flags,
                               const float* __restrict__ dinv,
                               float* __restrict__ agg, int E) {
    int is64 = flags[1];
    int lane = threadIdx.x & 63;
    int e = blockIdx.x * 4 + (threadIdx.x >> 6);
    if (e >= E) return;
    int s = ld_idx(ei, e, is64);
    int d = ld_idx(ei, (long long)E + e, is64);
    if ((unsigned)s >= (unsigned)NNODES || (unsigned)d >= (unsigned)NNODES) return;
    float nrm = dinv[s] * dinv[d];
    float v = H[(long long)s * 64 + lane] * nrm;
    atomicAdd(&agg[(long long)d * 64 + lane], v);
}

__global__ void relu_bias_kernel(float* __restrict__ H, const float* __restrict__ agg,
                                 const float* __restrict__ dinv, const void* b,
                                 const int* __restrict__ flags, int N) {
    int isf32 = flags[0];
    long long idx = (long long)blockIdx.x * blockDim.x + threadIdx.x;
    if (idx >= (long long)N * 64) return;
    int n = (int)(idx >> 6);
    int c = (int)(idx & 63);
    float dv = dinv[n];
    float v = agg[idx] + H[idx] * dv * dv + ld_f(b, c, isf32);
    H[idx] = v > 0.f ? v : 0.f;
}

__global__ void pool_fb_kernel(const float* __restrict__ agg, const float* __restrict__ Hg,
                               const float* __restrict__ dinv, const void* b,
                               const void* batch, const int* __restrict__ flags,
                               float* __restrict__ pooled, float* __restrict__ cnt, int N) {
    __shared__ float part[NG * 64];
    __shared__ float scnt[NG];
    int isf32 = flags[0];
    int b64   = flags[2];
    int tid = threadIdx.x;
    for (int i = tid; i < NG * 64; i += blockDim.x) part[i] = 0.f;
    if (tid < NG) scnt[tid] = 0.f;
    __syncthreads();
    int c = tid & 63;
    int sub = tid >> 6;
    float bc = ld_f(b, c, isf32);
    for (int n = blockIdx.x * 4 + sub; n < N; n += gridDim.x * 4) {
        int g = ld_idx(batch, n, b64);
        if ((unsigned)g >= (unsigned)NG) continue;
        float dv = dinv[n];
        float v = agg[(long long)n * 64 + c] + Hg[(long long)n * 64 + c] * dv * dv + bc;
        v = v > 0.f ? v : 0.f;
        atomicAdd(&part[g * 64 + c], v);
        if (c == 0) atomicAdd(&scnt[g], 1.0f);
    }
    __syncthreads();
    for (int i = tid; i < NG * 64; i += blockDim.x) {
        float v = part[i];
        if (v != 0.f) atomicAdd(&pooled[i], v);
    }
    if (tid < NG && scnt[tid] != 0.f) atomicAdd(&cnt[tid], scnt[tid]);
}

__global__ void zero_out_kernel(unsigned short* out, int n16) {
    int i = blockIdx.x * blockDim.x + threadIdx.x;
    if (i < n16) out[i] = 0;
}

extern "C" void kernel_launch(void* const* d_in, const int* in_sizes, int n_in,
                              void* d_out, int out_size, void* d_ws, size_t ws_size,
                              hipStream_t stream) {
    const void* x   = d_in[0];
    const void* ei  = d_in[1];   // [2, E] flat: src then dst
    const void* bat = d_in[2];
    const void* W1  = d_in[3];
    const void* b1  = d_in[4];
    const void* W2  = d_in[5];
    const void* b2  = d_in[6];
    const void* lw  = d_in[7];
    const void* lb  = d_in[8];

    const int N = NNODES, E = NEDGES;
    int* ws = (int*)d_ws;
    const int NT = (N + 63) / 64;    // gemm tiles

    // ---- CSR-path layout (words). staging aliases bufA (dead before GEMM1). ----
    const long long o_flags = 0;                          // 16
    const long long o_deg   = 16;                         // N
    const long long o_dinv  = 16 + (long long)N;          // N
    const long long o_rs    = 16 + 2LL * N;               // N+1
    const long long o_bcnt  = 300032;                     // PB*NBUCK+1 = 50177
    const long long o_pool  = 350272;                     // NG*64
    const long long o_cnt   = o_pool + NG * 64;           // NG
    const long long o_csr   = 354432;                     // E
    const long long o_bufA  = o_csr + E;                  // N*64 (= 2E words: staging fits)
    const long long o_bufB  = o_bufA + (long long)N * 64; // N*64
    const size_t need_csr = (size_t)(o_bufB + (long long)N * 64) * 4;   // ~65.4 MB

    // ---- fallback layout ----
    const size_t need_fb = (size_t)(204800 + 2LL * N * 64) * 4;

    if (ws_size >= need_csr) {
        int*   flags   = ws + o_flags;
        int*   deg     = ws + o_deg;
        float* dinv    = (float*)(ws + o_dinv);
        int*   rs      = ws + o_rs;
        int*   bcnt    = ws + o_bcnt;
        float* pooled  = (float*)(ws + o_pool);
        float* cnt     = (float*)(ws + o_cnt);
        int*   csr     = ws + o_csr;
        float* bufA    = (float*)(ws + o_bufA);
        float* bufB    = (float*)(ws + o_bufB);
        uint2* staging = (uint2*)(ws + o_bufA);           // alias: dead before GEMM1

        detect_kernel<<<1, 64, 0, stream>>>(x, ei, bat, flags);
        hipMemsetAsync(pooled, 0, (NG * 64 + NG) * sizeof(float), stream);

        // binned CSR build (no global atomics, dense writes)
        binA_count<<<PB, 256, 0, stream>>>(ei, flags, bcnt, E);
        binA_scan<<<1, 1024, 0, stream>>>(bcnt);
        binA_write<<<PB, 256, 0, stream>>>(ei, flags, bcnt, staging, E);
        binB_deg<<<NBUCK, 256, 0, stream>>>(staging, bcnt, deg);
        dinv_kernel<<<(N + 255) / 256, 256, 0, stream>>>(deg, dinv, N);
        scan_kernel<<<1, 1024, 0, stream>>>(deg, rs, N);
        binB_fill<<<NBUCK, 256, 0, stream>>>(staging, bcnt, rs, csr);

        // layer 1: gemm1 outputs dinv[row]*(x@W1); gather1 outputs dinv[row]*relu(...)
        gemm_tile<128, 0><<<NT, 256, 0, stream>>>(x, W1, flags, dinv, bufA, N);
        gather_kernel<<<(N + 3) / 4, 256, 0, stream>>>(bufA, rs, csr, dinv, b1, flags, dinv, bufB, N);
        // layer 2: row-scale already folded into bufB -> gemm2 needs no dscale
        gemm_tile<64, 1><<<NT, 256, 0, stream>>>(bufB, W2, flags, nullptr, bufA, N);
        gather_kernel<<<(N + 3) / 4, 256, 0, stream>>>(bufA, rs, csr, dinv, b2, flags, nullptr, bufB, N);

        pool2_kernel<<<512, 256, 0, stream>>>(bufB, bat, flags, pooled, cnt, N);
        final_kernel<<<1, 64, 0, stream>>>(pooled, cnt, lw, lb, flags, d_out);
    } else if (ws_size >= need_fb) {
        int*   flags  = ws;
        int*   deg    = ws + 16;
        float* dinv   = (float*)(ws + 16 + N);
        float* pooled = (float*)(ws + 16 + 2LL * N);
        float* cnt    = pooled + NG * 64;
        float* bufA   = (float*)(ws + 204800);
        float* bufB   = bufA + (long long)N * 64;

        detect_kernel<<<1, 64, 0, stream>>>(x, ei, bat, flags);
        hipMemsetAsync(deg, 0, N * sizeof(int), stream);
        hipMemsetAsync(pooled, 0, (NG * 64 + NG) * sizeof(float), stream);

        count_kernel<<<2048, 256, 0, stream>>>(ei, flags, deg, E);
        dinv_kernel<<<(N + 255) / 256, 256, 0, stream>>>(deg, dinv, N);

        gemm_tile<128, 0><<<NT, 256, 0, stream>>>(x, W1, flags, nullptr, bufA, N);
        hipMemsetAsync(bufB, 0, (size_t)N * 64 * sizeof(float), stream);
        scatter_kernel<<<(E + 3) / 4, 256, 0, stream>>>(bufA, ei, flags, dinv, bufB, E);
        relu_bias_kernel<<<((long long)N * 64 + 255) / 256, 256, 0, stream>>>(bufA, bufB, dinv, b1, flags, N);

        gemm_tile<64, 1><<<NT, 256, 0, stream>>>(bufA, W2, flags, nullptr, bufB, N);
        hipMemsetAsync(bufA, 0, (size_t)N * 64 * sizeof(float), stream);
        scatter_kernel<<<(E + 3) / 4, 256, 0, stream>>>(bufB, ei, flags, dinv, bufA, E);

        pool_fb_kernel<<<512, 256, 0, stream>>>(bufA, bufB, dinv, b2, bat, flags, pooled, cnt, N);
        final_kernel<<<1, 64, 0, stream>>>(pooled, cnt, lw, lb, flags, d_out);
    } else {
        zero_out_kernel<<<(out_size * 2 + 255) / 256, 256, 0, stream>>>(
            (unsigned short*)d_out, out_size);
    }
}

// Round 8
// 647.180 us; speedup vs baseline: 2.4316x; 1.2684x over previous
//
#include <hip/hip_runtime.h>
#include <hip/hip_bf16.h>

#define NNODES 100000
#define NEDGES 3200000
#define NG     64
#define NBUCK  196          // ceil(NNODES/512) buckets of 512 dst nodes
#define PB     256          // phase-A partition blocks
#define SCAN_M (PB * NBUCK) // 50176
#define SCAN_NB ((SCAN_M + 1023) / 1024)   // 49

// ---------- dtype-flexible loads (flags are wave-uniform) ----------
__device__ __forceinline__ int ld_idx(const void* p, long long i, int is64) {
    if (is64) return (int)((const long long*)p)[i];
    return ((const int*)p)[i];
}
__device__ __forceinline__ float ld_f(const void* p, long long i, int isf32) {
    if (isf32) return ((const float*)p)[i];
    return __bfloat162float(((const __hip_bfloat16*)p)[i]);
}
__device__ __forceinline__ float bfbits(unsigned b) {
    return __uint_as_float(b << 16);
}

// ---------- runtime dtype detection (parallel, 256 threads) ----------
__global__ void detect_kernel(const void* x, const void* ei, const void* bat, int* flags) {
    __shared__ int f[3];
    int t = threadIdx.x;
    if (t < 3) f[t] = 0;
    __syncthreads();
    const unsigned short* u = (const unsigned short*)x;
    int e = (u[t] >> 7) & 0xFF;
    if (e >= 0x90) atomicOr(&f[0], 1);                 // fp32-reinterpret signature
    const unsigned* w = (const unsigned*)ei;
    if (w[2 * t + 1] != 0u) atomicOr(&f[1], 1);        // odd word nonzero -> int32
    const unsigned* bw = (const unsigned*)bat;
    if (bw[50001 + 2 * t] != 0u) atomicOr(&f[2], 1);   // mid-array odd words
    __syncthreads();
    if (t == 0) { flags[0] = f[0]; flags[1] = !f[1]; flags[2] = !f[2]; }
}

// ---------- phase A1: per-(bucket,block) edge counts (LDS only) ----------
__global__ void binA_count(const void* ei, const int* __restrict__ flags,
                           int* __restrict__ bcnt, int E) {
    __shared__ int cnt[NBUCK];
    int is64 = flags[1];
    for (int i = threadIdx.x; i < NBUCK; i += 256) cnt[i] = 0;
    __syncthreads();
    const int chunk = (E + PB - 1) / PB;
    int beg = blockIdx.x * chunk, end = min(E, beg + chunk);
    for (int i = beg + threadIdx.x; i < end; i += 256) {
        int s = ld_idx(ei, i, is64);
        int d = ld_idx(ei, (long long)E + i, is64);
        if ((unsigned)s < (unsigned)NNODES && (unsigned)d < (unsigned)NNODES)
            atomicAdd(&cnt[d >> 9], 1);
    }
    __syncthreads();
    for (int i = threadIdx.x; i < NBUCK; i += 256)
        bcnt[i * PB + blockIdx.x] = cnt[i];     // bucket-major for scan
}

// ---------- parallel 3-phase exclusive scan over bcnt[SCAN_M] ----------
__global__ void scanP1(int* __restrict__ a, int* __restrict__ sums) {
    __shared__ int ls[1024];
    int t = threadIdx.x;
    int i = blockIdx.x * 1024 + t;
    int v = (i < SCAN_M) ? a[i] : 0;
    ls[t] = v;
    __syncthreads();
    for (int off = 1; off < 1024; off <<= 1) {
        int p = (t >= off) ? ls[t - off] : 0;
        __syncthreads();
        ls[t] += p;
        __syncthreads();
    }
    if (i < SCAN_M) a[i] = ls[t] - v;           // exclusive within block
    if (t == 1023) sums[blockIdx.x] = ls[1023]; // block total
}

__global__ void scanP2(int* __restrict__ sums) {
    __shared__ int ls[SCAN_NB];
    int t = threadIdx.x;
    if (t < SCAN_NB) ls[t] = sums[t];
    __syncthreads();
    if (t == 0) {
        int run = 0;
        for (int i = 0; i < SCAN_NB; ++i) { int c = ls[i]; ls[i] = run; run += c; }
        sums[SCAN_NB] = run;                    // grand total
    }
    __syncthreads();
    if (t < SCAN_NB) sums[t] = ls[t];
}

__global__ void scanP3(int* __restrict__ a, const int* __restrict__ sums) {
    int i = blockIdx.x * 1024 + threadIdx.x;
    if (i < SCAN_M) a[i] += sums[blockIdx.x];
    if (i == 0) a[SCAN_M] = sums[SCAN_NB];      // bcnt[M] = total
}

// ---------- phase A3: partition edges into bucket-ordered staging (s,d) ----------
__global__ void binA_write(const void* ei, const int* __restrict__ flags,
                           const int* __restrict__ bcnt, uint2* __restrict__ staging, int E) {
    __shared__ int cur[NBUCK];
    int is64 = flags[1];
    for (int i = threadIdx.x; i < NBUCK; i += 256) cur[i] = bcnt[i * PB + blockIdx.x];
    __syncthreads();
    const int chunk = (E + PB - 1) / PB;
    int beg = blockIdx.x * chunk, end = min(E, beg + chunk);
    for (int i = beg + threadIdx.x; i < end; i += 256) {
        int s = ld_idx(ei, i, is64);
        int d = ld_idx(ei, (long long)E + i, is64);
        if ((unsigned)s < (unsigned)NNODES && (unsigned)d < (unsigned)NNODES) {
            int pos = atomicAdd(&cur[d >> 9], 1);
            staging[pos] = make_uint2((unsigned)s, (unsigned)d);
        }
    }
}

// ---------- phase B1 (fused): per-bucket degrees -> rs (local scan + bucket base) + dinv ----------
__global__ void binB_deg_rs(const uint2* __restrict__ staging, const int* __restrict__ bcnt,
                            int* __restrict__ rs, float* __restrict__ dinv) {
    __shared__ int dcnt[512];
    __shared__ int ls[256];
    int b = blockIdx.x;
    int lo = b << 9;
    int t = threadIdx.x;
    for (int i = t; i < 512; i += 256) dcnt[i] = 0;
    __syncthreads();
    int beg = bcnt[b * PB], end = bcnt[(b + 1) * PB];
    for (int i = beg + t; i < end; i += 256)
        atomicAdd(&dcnt[staging[i].y - lo], 1);
    __syncthreads();
    int a  = dcnt[2 * t];
    int b2 = dcnt[2 * t + 1];
    int csum = a + b2;
    ls[t] = csum;
    __syncthreads();
    for (int off = 1; off < 256; off <<= 1) {
        int p = (t >= off) ? ls[t - off] : 0;
        __syncthreads();
        ls[t] += p;
        __syncthreads();
    }
    int pref = ls[t] - csum;                    // exclusive prefix of this 2-chunk
    int base = beg;
    int n0 = lo + 2 * t, n1 = lo + 2 * t + 1;
    if (n0 < NNODES) { rs[n0] = base + pref;     dinv[n0] = rsqrtf((float)a + 1.0f); }
    if (n1 < NNODES) { rs[n1] = base + pref + a; dinv[n1] = rsqrtf((float)b2 + 1.0f); }
    if (b == NBUCK - 1 && t == 0) rs[NNODES] = bcnt[SCAN_M];
}

// ---------- phase B2: per-bucket CSR fill (LDS cursors; dense 65KB write regions) ----------
__global__ void binB_fill(const uint2* __restrict__ staging, const int* __restrict__ bcnt,
                          const int* __restrict__ rs, int* __restrict__ csr) {
    __shared__ int cur[512];
    int b = blockIdx.x;
    int lo = b << 9;
    for (int i = threadIdx.x; i < 512; i += 256)
        cur[i] = (lo + i < NNODES) ? rs[lo + i] : 0;
    __syncthreads();
    int beg = bcnt[b * PB], end = bcnt[(b + 1) * PB];
    for (int i = beg + threadIdx.x; i < end; i += 256) {
        uint2 u = staging[i];
        int pos = atomicAdd(&cur[u.y - lo], 1);
        csr[pos] = (int)u.x;
    }
}

// ---------- GEMM: X-tile (64 rows) + W both staged in LDS; coalesced global loads only ----------
// SRC==0: X has detected dtype; SRC==1: X is fp32 workspace
template <int K, int SRC>
__global__ __launch_bounds__(256)
void gemm_tile(const void* __restrict__ X, const void* __restrict__ W,
               const int* __restrict__ flags, const float* __restrict__ dscale,
               float* __restrict__ Out, int N) {
    __shared__ float lsW[K * 64];     // [k][c]
    __shared__ float lsX[64 * K];     // [r][k], fp32 after conversion
    int isf32 = flags[0];
    for (int i = threadIdx.x; i < K * 64; i += 256) lsW[i] = ld_f(W, i, isf32);

    int c  = threadIdx.x & 63;
    int wv = threadIdx.x >> 6;        // wave owns rows [wv*16, wv*16+16)
    int ntiles = (N + 63) >> 6;

    for (int t = blockIdx.x; t < ntiles; t += gridDim.x) {
        int row0 = t << 6;
        int nrows = min(64, N - row0);
        int total = nrows * K;
        __syncthreads();              // prev-tile readers done (also covers lsW on 1st iter)
        if (SRC == 1 || isf32) {
            const float* Xb = (const float*)X + (long long)row0 * K;
            for (int i = threadIdx.x; i < total; i += 256) lsX[i] = Xb[i];
        } else {
            const unsigned short* Xb = (const unsigned short*)X + (long long)row0 * K;
            for (int i = threadIdx.x; i < total; i += 256) lsX[i] = bfbits((unsigned)Xb[i]);
        }
        __syncthreads();

        int rbase = wv * 16;
        float acc[16];
#pragma unroll
        for (int r = 0; r < 16; ++r) acc[r] = 0.f;
#pragma unroll 1
        for (int kc = 0; kc < K; kc += 8) {
            float w0 = lsW[(kc + 0) * 64 + c], w1 = lsW[(kc + 1) * 64 + c];
            float w2 = lsW[(kc + 2) * 64 + c], w3 = lsW[(kc + 3) * 64 + c];
            float w4 = lsW[(kc + 4) * 64 + c], w5 = lsW[(kc + 5) * 64 + c];
            float w6 = lsW[(kc + 6) * 64 + c], w7 = lsW[(kc + 7) * 64 + c];
#pragma unroll
            for (int r = 0; r < 16; ++r) {
                const float4* xp = (const float4*)&lsX[(rbase + r) * K + kc];
                float4 xa = xp[0], xb = xp[1];   // LDS broadcast reads
                acc[r] += xa.x * w0 + xa.y * w1 + xa.z * w2 + xa.w * w3
                        + xb.x * w4 + xb.y * w5 + xb.z * w6 + xb.w * w7;
            }
        }
        long long ob = (long long)row0 * 64;
#pragma unroll
        for (int r = 0; r < 16; ++r) {
            int rr = rbase + r;
            if (rr < nrows) {
                float v = acc[r];
                if (dscale) v *= dscale[row0 + rr];
                Out[ob + (long long)rr * 64 + c] = v;
            }
        }
    }
}

// ---------- CSR gather over pre-scaled Hs; optional output pre-scale for next layer ----------
__global__ void gather_kernel(const float* __restrict__ Hs,
                              const int* __restrict__ row_start,
                              const int* __restrict__ csr_src,
                              const float* __restrict__ dinv,
                              const void* bias, const int* __restrict__ flags,
                              const float* __restrict__ out_scale,
                              float* __restrict__ Hout, int N) {
    int isf32 = flags[0];
    int c = threadIdx.x & 63;
    int n = blockIdx.x * 4 + (threadIdx.x >> 6);
    if (n >= N) return;
    int beg = row_start[n], end = row_start[n + 1];
    float a0 = Hs[(long long)n * 64 + c];     // self-loop term (already ×dinv[n])
    float a1 = 0.f;
    int i = beg;
    for (; i + 3 < end; i += 4) {
        int s0 = csr_src[i], s1 = csr_src[i + 1], s2 = csr_src[i + 2], s3 = csr_src[i + 3];
        float h0 = Hs[(long long)s0 * 64 + c];
        float h1 = Hs[(long long)s1 * 64 + c];
        float h2 = Hs[(long long)s2 * 64 + c];
        float h3 = Hs[(long long)s3 * 64 + c];
        a0 += h0 + h2;
        a1 += h1 + h3;
    }
    for (; i < end; ++i)
        a0 += Hs[(long long)csr_src[i] * 64 + c];
    float v = (a0 + a1) * dinv[n] + ld_f(bias, c, isf32);
    float r = v > 0.f ? v : 0.f;
    if (out_scale) r *= out_scale[n];
    Hout[(long long)n * 64 + c] = r;
}

// ---------- pooling over final H ----------
__global__ void pool2_kernel(const float* __restrict__ H, const void* batch,
                             const int* __restrict__ flags,
                             float* __restrict__ pooled, float* __restrict__ cnt, int N) {
    __shared__ float part[NG * 64];
    __shared__ float scnt[NG];
    int b64 = flags[2];
    int tid = threadIdx.x;
    for (int i = tid; i < NG * 64; i += blockDim.x) part[i] = 0.f;
    if (tid < NG) scnt[tid] = 0.f;
    __syncthreads();
    int c = tid & 63;
    int sub = tid >> 6;
    for (int n = blockIdx.x * 4 + sub; n < N; n += gridDim.x * 4) {
        int g = ld_idx(batch, n, b64);
        if ((unsigned)g >= (unsigned)NG) continue;
        atomicAdd(&part[g * 64 + c], H[(long long)n * 64 + c]);
        if (c == 0) atomicAdd(&scnt[g], 1.0f);
    }
    __syncthreads();
    for (int i = tid; i < NG * 64; i += blockDim.x) {
        float v = part[i];
        if (v != 0.f) atomicAdd(&pooled[i], v);
    }
    if (tid < NG && scnt[tid] != 0.f) atomicAdd(&cnt[tid], scnt[tid]);
}

// ---------- final ----------
__global__ void final_kernel(const float* __restrict__ pooled, const float* __restrict__ cnt,
                             const void* lw, const void* lb,
                             const int* __restrict__ flags, void* out) {
    int isf32 = flags[0];
    int g = threadIdx.x;
    if (g >= NG) return;
    float inv = 1.0f / fmaxf(cnt[g], 1.0f);
    float logits[10];
    for (int c = 0; c < 10; ++c) logits[c] = ld_f(lb, c, isf32);
    for (int k = 0; k < 64; ++k) {
        float m = pooled[g * 64 + k] * inv;
        for (int c = 0; c < 10; ++c)
            logits[c] += m * ld_f(lw, k * 10 + c, isf32);
    }
    float mx = logits[0];
    for (int c = 1; c < 10; ++c) mx = fmaxf(mx, logits[c]);
    float se = 0.f;
    for (int c = 0; c < 10; ++c) se += __expf(logits[c] - mx);
    float lse = mx + __logf(se);
    if (isf32) {
        float* o = (float*)out;
        for (int c = 0; c < 10; ++c) o[g * 10 + c] = logits[c] - lse;
    } else {
        __hip_bfloat16* o = (__hip_bfloat16*)out;
        for (int c = 0; c < 10; ++c) o[g * 10 + c] = __float2bfloat16(logits[c] - lse);
    }
}

// ---------- fallback pipeline kernels (round-2 proven, atomic scatter) ----------
__global__ void count_kernel(const void* ei, const int* __restrict__ flags,
                             int* __restrict__ deg, int E) {
    int is64 = flags[1];
    int i = blockIdx.x * blockDim.x + threadIdx.x;
    int stride = gridDim.x * blockDim.x;
    for (; i < E; i += stride) {
        int d = ld_idx(ei, (long long)E + i, is64);
        if ((unsigned)d < (unsigned)NNODES) atomicAdd(&deg[d], 1);
    }
}

__global__ void dinv_kernel(const int* __restrict__ deg, float* __restrict__ dinv, int N) {
    int i = blockIdx.x * blockDim.x + threadIdx.x;
    if (i < N) dinv[i] = rsqrtf((float)deg[i] + 1.0f);
}

__global__ void scatter_kernel(const float* __restrict__ H, const void* ei,
                               const int* __restrict__ flags,
                               const float* __restrict__ dinv,
                               float* __restrict__ agg, int E) {
    int is64 = flags[1];
    int lane = threadIdx.x & 63;
    int e = blockIdx.x * 4 + (threadIdx.x >> 6);
    if (e >= E) return;
    int s = ld_idx(ei, e, is64);
    int d = ld_idx(ei, (long long)E + e, is64);
    if ((unsigned)s >= (unsigned)NNODES || (unsigned)d >= (unsigned)NNODES) return;
    float nrm = dinv[s] * dinv[d];
    float v = H[(long long)s * 64 + lane] * nrm;
    atomicAdd(&agg[(long long)d * 64 + lane], v);
}

__global__ void relu_bias_kernel(float* __restrict__ H, const float* __restrict__ agg,
                                 const float* __restrict__ dinv, const void* b,
                                 const int* __restrict__ flags, int N) {
    int isf32 = flags[0];
    long long idx = (long long)blockIdx.x * blockDim.x + threadIdx.x;
    if (idx >= (long long)N * 64) return;
    int n = (int)(idx >> 6);
    int c = (int)(idx & 63);
    float dv = dinv[n];
    float v = agg[idx] + H[idx] * dv * dv + ld_f(b, c, isf32);
    H[idx] = v > 0.f ? v : 0.f;
}

__global__ void pool_fb_kernel(const float* __restrict__ agg, const float* __restrict__ Hg,
                               const float* __restrict__ dinv, const void* b,
                               const void* batch, const int* __restrict__ flags,
                               float* __restrict__ pooled, float* __restrict__ cnt, int N) {
    __shared__ float part[NG * 64];
    __shared__ float scnt[NG];
    int isf32 = flags[0];
    int b64   = flags[2];
    int tid = threadIdx.x;
    for (int i = tid; i < NG * 64; i += blockDim.x) part[i] = 0.f;
    if (tid < NG) scnt[tid] = 0.f;
    __syncthreads();
    int c = tid & 63;
    int sub = tid >> 6;
    float bc = ld_f(b, c, isf32);
    for (int n = blockIdx.x * 4 + sub; n < N; n += gridDim.x * 4) {
        int g = ld_idx(batch, n, b64);
        if ((unsigned)g >= (unsigned)NG) continue;
        float dv = dinv[n];
        float v = agg[(long long)n * 64 + c] + Hg[(long long)n * 64 + c] * dv * dv + bc;
        v = v > 0.f ? v : 0.f;
        atomicAdd(&part[g * 64 + c], v);
        if (c == 0) atomicAdd(&scnt[g], 1.0f);
    }
    __syncthreads();
    for (int i = tid; i < NG * 64; i += blockDim.x) {
        float v = part[i];
        if (v != 0.f) atomicAdd(&pooled[i], v);
    }
    if (tid < NG && scnt[tid] != 0.f) atomicAdd(&cnt[tid], scnt[tid]);
}

__global__ void scan_kernel(int* __restrict__ deg, int* __restrict__ row_start, int N) {
    __shared__ int ls[1024];
    const int CH = (N + 1023) / 1024;
    int t = threadIdx.x;
    int beg = t * CH, end = min(N, beg + CH);
    int sum = 0;
    for (int i = beg; i < end; ++i) sum += deg[i];
    ls[t] = sum;
    __syncthreads();
    for (int off = 1; off < 1024; off <<= 1) {
        int v = (t >= off) ? ls[t - off] : 0;
        __syncthreads();
        ls[t] += v;
        __syncthreads();
    }
    int run = ls[t] - sum;
    for (int i = beg; i < end; ++i) {
        row_start[i] = run;
        run += deg[i];
    }
    if (t == 1023) row_start[N] = ls[1023];
}

__global__ void zero_out_kernel(unsigned short* out, int n16) {
    int i = blockIdx.x * blockDim.x + threadIdx.x;
    if (i < n16) out[i] = 0;
}

extern "C" void kernel_launch(void* const* d_in, const int* in_sizes, int n_in,
                              void* d_out, int out_size, void* d_ws, size_t ws_size,
                              hipStream_t stream) {
    const void* x   = d_in[0];
    const void* ei  = d_in[1];   // [2, E] flat: src then dst
    const void* bat = d_in[2];
    const void* W1  = d_in[3];
    const void* b1  = d_in[4];
    const void* W2  = d_in[5];
    const void* b2  = d_in[6];
    const void* lw  = d_in[7];
    const void* lb  = d_in[8];

    const int N = NNODES, E = NEDGES;
    int* ws = (int*)d_ws;
    const int NT = (N + 63) / 64;    // gemm tiles

    // ---- CSR-path layout (words). staging aliases bufA (dead before GEMM1). ----
    const long long o_flags = 0;                          // 16
    const long long o_deg   = 16;                         // N (CSR path: reused for scan sums)
    const long long o_dinv  = 16 + (long long)N;          // N
    const long long o_rs    = 16 + 2LL * N;               // N+1
    const long long o_bcnt  = 300032;                     // SCAN_M+1 = 50177
    const long long o_pool  = 350272;                     // NG*64
    const long long o_cnt   = o_pool + NG * 64;           // NG
    const long long o_csr   = 354432;                     // E
    const long long o_bufA  = o_csr + E;                  // N*64 (= 2E words: staging fits)
    const long long o_bufB  = o_bufA + (long long)N * 64; // N*64
    const size_t need_csr = (size_t)(o_bufB + (long long)N * 64) * 4;   // ~65.4 MB

    // ---- fallback layout ----
    const size_t need_fb = (size_t)(204800 + 2LL * N * 64) * 4;

    if (ws_size >= need_csr) {
        int*   flags   = ws + o_flags;
        int*   bsums   = ws + o_deg;       // SCAN_NB+1 words (deg region unused in CSR path)
        float* dinv    = (float*)(ws + o_dinv);
        int*   rs      = ws + o_rs;
        int*   bcnt    = ws + o_bcnt;
        float* pooled  = (float*)(ws + o_pool);
        float* cnt     = (float*)(ws + o_cnt);
        int*   csr     = ws + o_csr;
        float* bufA    = (float*)(ws + o_bufA);
        float* bufB    = (float*)(ws + o_bufB);
        uint2* staging = (uint2*)(ws + o_bufA);           // alias: dead before GEMM1

        detect_kernel<<<1, 256, 0, stream>>>(x, ei, bat, flags);
        hipMemsetAsync(pooled, 0, (NG * 64 + NG) * sizeof(float), stream);

        // binned CSR build: no global atomics, no serial scans
        binA_count<<<PB, 256, 0, stream>>>(ei, flags, bcnt, E);
        scanP1<<<SCAN_NB, 1024, 0, stream>>>(bcnt, bsums);
        scanP2<<<1, 64, 0, stream>>>(bsums);
        scanP3<<<SCAN_NB, 1024, 0, stream>>>(bcnt, bsums);
        binA_write<<<PB, 256, 0, stream>>>(ei, flags, bcnt, staging, E);
        binB_deg_rs<<<NBUCK, 256, 0, stream>>>(staging, bcnt, rs, dinv);
        binB_fill<<<NBUCK, 256, 0, stream>>>(staging, bcnt, rs, csr);

        // layer 1: gemm1 outputs dinv[row]*(x@W1); gather1 outputs dinv[row]*relu(...)
        gemm_tile<128, 0><<<NT, 256, 0, stream>>>(x, W1, flags, dinv, bufA, N);
        gather_kernel<<<(N + 3) / 4, 256, 0, stream>>>(bufA, rs, csr, dinv, b1, flags, dinv, bufB, N);
        // layer 2: row-scale already folded into bufB -> gemm2 needs no dscale
        gemm_tile<64, 1><<<NT, 256, 0, stream>>>(bufB, W2, flags, nullptr, bufA, N);
        gather_kernel<<<(N + 3) / 4, 256, 0, stream>>>(bufA, rs, csr, dinv, b2, flags, nullptr, bufB, N);

        pool2_kernel<<<512, 256, 0, stream>>>(bufB, bat, flags, pooled, cnt, N);
        final_kernel<<<1, 64, 0, stream>>>(pooled, cnt, lw, lb, flags, d_out);
    } else if (ws_size >= need_fb) {
        int*   flags  = ws;
        int*   deg    = ws + 16;
        float* dinv   = (float*)(ws + 16 + N);
        float* pooled = (float*)(ws + 16 + 2LL * N);
        float* cnt    = pooled + NG * 64;
        float* bufA   = (float*)(ws + 204800);
        float* bufB   = bufA + (long long)N * 64;

        detect_kernel<<<1, 256, 0, stream>>>(x, ei, bat, flags);
        hipMemsetAsync(deg, 0, N * sizeof(int), stream);
        hipMemsetAsync(pooled, 0, (NG * 64 + NG) * sizeof(float), stream);

        count_kernel<<<2048, 256, 0, stream>>>(ei, flags, deg, E);
        dinv_kernel<<<(N + 255) / 256, 256, 0, stream>>>(deg, dinv, N);

        gemm_tile<128, 0><<<NT, 256, 0, stream>>>(x, W1, flags, nullptr, bufA, N);
        hipMemsetAsync(bufB, 0, (size_t)N * 64 * sizeof(float), stream);
        scatter_kernel<<<(E + 3) / 4, 256, 0, stream>>>(bufA, ei, flags, dinv, bufB, E);
        relu_bias_kernel<<<((long long)N * 64 + 255) / 256, 256, 0, stream>>>(bufA, bufB, dinv, b1, flags, N);

        gemm_tile<64, 1><<<NT, 256, 0, stream>>>(bufA, W2, flags, nullptr, bufB, N);
        hipMemsetAsync(bufA, 0, (size_t)N * 64 * sizeof(float), stream);
        scatter_kernel<<<(E + 3) / 4, 256, 0, stream>>>(bufB, ei, flags, dinv, bufA, E);

        pool_fb_kernel<<<512, 256, 0, stream>>>(bufA, bufB, dinv, b2, bat, flags, pooled, cnt, N);
        final_kernel<<<1, 64, 0, stream>>>(pooled, cnt, lw, lb, flags, d_out);
    } else {
        zero_out_kernel<<<(out_size * 2 + 255) / 256, 256, 0, stream>>>(
            (unsigned short*)d_out, out_size);
    }
}